// Round 4
// baseline (1018.023 us; speedup 1.0000x reference)
//
#include <hip/hip_runtime.h>

// Problem constants (from reference)
#define Bx 4
#define Nn 10000
#define Ee 160000
#define Qq 256
#define Dd 128
#define Mm 64
#define Uu 126
#define Hh 128
#define Pp 7

// N padded to groups of 8 (1250 groups) + 2 pad groups for ragged K-tail
#define KG 1252

typedef unsigned short u16;
typedef __bf16 bf16x8 __attribute__((ext_vector_type(8)));
typedef float f32x4 __attribute__((ext_vector_type(4)));

__device__ __forceinline__ float b2f(u16 h){
  unsigned u = ((unsigned)h) << 16; float f; __builtin_memcpy(&f, &u, 4); return f;
}
__device__ __forceinline__ u16 f2b(float f){
  unsigned u; __builtin_memcpy(&u, &f, 4);
  u = (u + 0x7FFFu + ((u >> 16) & 1u)) >> 16;   // RNE
  return (u16)u;
}
__device__ __forceinline__ float ldin(const void* p, long i, int flag){
  return flag ? b2f(((const u16*)p)[i]) : ((const float*)p)[i];
}
__device__ __forceinline__ void acc2bf(float& a0, float& a1, unsigned v){
  a0 += b2f((u16)(v & 0xffffu));
  a1 += b2f((u16)(v >> 16));
}

// ---------------- dtype probe ----------------
__global__ void probe_kernel(const void* in0, int* flag){
  if (threadIdx.x == 0 && blockIdx.x == 0){
    const u16* p = (const u16*)in0;
    int cnt = 0;
    for (int i = 0; i < 256; i++){
      float a = fabsf(b2f(p[i]));
      if (a > 0.0009765625f && a < 32.0f) cnt++;
    }
    *flag = (cnt >= 240) ? 1 : 0;
  }
}

// ---------------- weight prep: convert + swizzle to MFMA B-frag layout ----------------
__global__ void prep_kernel(const void* w1e, const void* b1e, const void* w2e, const void* b2e,
                            const void* w1n, const void* b1n, const void* w2n, const void* b2n,
                            const int* __restrict__ flag,
                            u16* w1e_s, u16* w2e_s, u16* w1n_s, u16* w2n_s,
                            float* b1e_f, float* b2e_f, float* b1n_f, float* b2n_f)
{
  int f = *flag;
  for (int idx = blockIdx.x * blockDim.x + threadIdx.x; idx < 82368; idx += gridDim.x * blockDim.x){
    if (idx < 32768){                                   // w1e (256,128)
      int k = idx >> 7, h = idx & 127;
      w1e_s[(k >> 3) * 1024 + h * 8 + (k & 7)] = f2b(ldin(w1e, idx, f));
    } else if (idx < 40960){                            // w2e (128,64)
      int i2 = idx - 32768; int k = i2 >> 6, m2 = i2 & 63;
      w2e_s[(k >> 3) * 512 + m2 * 8 + (k & 7)] = f2b(ldin(w2e, i2, f));
    } else if (idx < 65536){                            // w1n (192,128)
      int i2 = idx - 40960; int k = i2 >> 7, h = i2 & 127;
      w1n_s[(k >> 3) * 1024 + h * 8 + (k & 7)] = f2b(ldin(w1n, i2, f));
    } else if (idx < 81920){                            // w2n (128,126) padded to 128 cols
      int i2 = idx - 65536; int k = i2 >> 7, u = i2 & 127;
      float v = (u < 126) ? ldin(w2n, (long)k * 126 + u, f) : 0.f;
      w2n_s[(k >> 3) * 1024 + u * 8 + (k & 7)] = f2b(v);
    } else if (idx < 82048){ b1e_f[idx - 81920] = ldin(b1e, idx - 81920, f); }
    else if (idx < 82112){ b2e_f[idx - 82048] = ldin(b2e, idx - 82048, f); }
    else if (idx < 82240){ b1n_f[idx - 82112] = ldin(b1n, idx - 82112, f); }
    else { int j = idx - 82240; b2n_f[j] = (j < 126) ? ldin(b2n, j, f) : 0.f; }
  }
}

// ---------------- init: f32 master states + bf16 mirror ----------------
__global__ void init_states_kernel(const void* in0, const int* __restrict__ flag,
                                   float* __restrict__ sf, u16* __restrict__ sbm)
{
  int f = *flag;
  const long total = (long)Bx * Nn * Dd;
  for (long i = (long)blockIdx.x * blockDim.x + threadIdx.x; i < total; i += (long)gridDim.x * blockDim.x){
    float v = ldin(in0, i, f);
    sf[i] = v; sbm[i] = f2b(v);
  }
}

// ---------------- CSR build ----------------
__global__ void count_kernel(const int* __restrict__ snk, int* __restrict__ cnt){
  int i = blockIdx.x * blockDim.x + threadIdx.x;
  if (i < Ee) atomicAdd(&cnt[snk[i]], 1);
}
__global__ void scan_kernel(const int* __restrict__ cnt, int* __restrict__ rowp){
  __shared__ int tot[1024];
  int t = threadIdx.x;
  int base = t * 10;
  int local[10]; int s = 0;
  #pragma unroll
  for (int i = 0; i < 10; i++){
    int v = (base + i < Nn) ? cnt[base + i] : 0;
    local[i] = s; s += v;
  }
  tot[t] = s;
  __syncthreads();
  for (int o = 1; o < 1024; o <<= 1){
    int v = (t >= o) ? tot[t - o] : 0;
    __syncthreads();
    tot[t] += v;
    __syncthreads();
  }
  int prefix = (t == 0) ? 0 : tot[t - 1];
  #pragma unroll
  for (int i = 0; i < 10; i++)
    if (base + i < Nn) rowp[base + i] = prefix + local[i];
  if (t == 1023) rowp[Nn] = tot[1023];
}
// perm[e] = CSR position of edge e (messages get written pre-sorted by sink)
__global__ void fill_kernel(const int* __restrict__ snk, const int* __restrict__ rowp,
                            int* __restrict__ cnt, int* __restrict__ perm){
  int i = blockIdx.x * blockDim.x + threadIdx.x;
  if (i < Ee){
    int s = snk[i];
    int p = rowp[s] + atomicAdd(&cnt[s], 1);
    perm[i] = p;
  }
}

// ---------------- edge MLP v4 ----------------
// 256-edge tiles, 2 M-subtiles/wave (each LDS B-frag feeds 2 MFMAs), XCD-affine
// batch mapping, register-prefetched A-frags per K-half, CSR-permuted full-line stores.
__global__ __launch_bounds__(512) void edge_kernel(
  const u16* __restrict__ sbm, const int* __restrict__ src, const int* __restrict__ snk,
  const int* __restrict__ perm,
  const u16* __restrict__ w1s, const u16* __restrict__ w2s,
  const float* __restrict__ b1f, const float* __restrict__ b2f2,
  u16* __restrict__ msg)
{
  __shared__ __align__(16) u16 w1h[16384];     // 32KB: one K-half of w1e, swizzled
  __shared__ __align__(16) u16 Yt[128 * 72];   // 18KB: hidden phase / store transpose
  __shared__ float b1l[128];
  __shared__ float b2l[64];
  int tid = threadIdx.x;
  if (tid < 128) b1l[tid] = b1f[tid];
  else if (tid < 192) b2l[tid - 128] = b2f2[tid - 128];

  // blockIdx % 8 -> XCD; batch pinned to an XCD pair. 2504 blocks; tile<625 guard.
  int b = (blockIdx.x & 7) >> 1;
  int tile = ((blockIdx.x >> 3) << 1) + (blockIdx.x & 1);
  if (tile >= 625) return;                     // uniform per block; before any barrier
  int e0 = tile * 256;
  int w = tid >> 6, lane = tid & 63, m = lane & 15, quad = lane >> 4;
  int ebase = e0 + w * 32;
  int eA = ebase + m, eB = ebase + 16 + m;
  int src0 = src[eA], src1 = src[eB];
  int snk0 = snk[eA], snk1 = snk[eB];
  const u16* sbase = sbm + (((size_t)b * Nn) << 7);

  // prefetch src-rows (hide gather latency under half-0 staging)
  bf16x8 aS0[4], aS1[4];
  {
    const u16* r0 = sbase + ((size_t)src0 << 7);
    const u16* r1 = sbase + ((size_t)src1 << 7);
    #pragma unroll
    for (int lk = 0; lk < 4; lk++){
      aS0[lk] = *(const bf16x8*)(r0 + lk * 32 + quad * 8);
      aS1[lk] = *(const bf16x8*)(r1 + lk * 32 + quad * 8);
    }
  }

  f32x4 acc1[2][8];
  const f32x4 z4 = {0.f, 0.f, 0.f, 0.f};
  #pragma unroll
  for (int s = 0; s < 2; s++)
    #pragma unroll
    for (int ct = 0; ct < 8; ct++) acc1[s][ct] = z4;

  // ---- layer 1, K-half 0 (src rows) ----
  {
    const uint4* g = (const uint4*)(w1s);
    uint4* l = (uint4*)w1h;
    #pragma unroll
    for (int i = 0; i < 4; i++) l[tid + i * 512] = g[tid + i * 512];
  }
  __syncthreads();
  #pragma unroll
  for (int lk = 0; lk < 4; lk++){
    #pragma unroll
    for (int ct = 0; ct < 8; ct++){
      bf16x8 bv = *(const bf16x8*)(w1h + (((lk * 4 + quad) << 7) + ct * 16 + m) * 8);
      acc1[0][ct] = __builtin_amdgcn_mfma_f32_16x16x32_bf16(aS0[lk], bv, acc1[0][ct], 0, 0, 0);
      acc1[1][ct] = __builtin_amdgcn_mfma_f32_16x16x32_bf16(aS1[lk], bv, acc1[1][ct], 0, 0, 0);
    }
  }
  // prefetch snk-rows (overlaps half-1 staging wait)
  bf16x8 aK0[4], aK1[4];
  {
    const u16* r0 = sbase + ((size_t)snk0 << 7);
    const u16* r1 = sbase + ((size_t)snk1 << 7);
    #pragma unroll
    for (int lk = 0; lk < 4; lk++){
      aK0[lk] = *(const bf16x8*)(r0 + lk * 32 + quad * 8);
      aK1[lk] = *(const bf16x8*)(r1 + lk * 32 + quad * 8);
    }
  }
  __syncthreads();
  // ---- layer 1, K-half 1 (snk rows) ----
  {
    const uint4* g = (const uint4*)(w1s + 16384);
    uint4* l = (uint4*)w1h;
    #pragma unroll
    for (int i = 0; i < 4; i++) l[tid + i * 512] = g[tid + i * 512];
  }
  __syncthreads();
  #pragma unroll
  for (int lk = 0; lk < 4; lk++){
    #pragma unroll
    for (int ct = 0; ct < 8; ct++){
      bf16x8 bv = *(const bf16x8*)(w1h + (((lk * 4 + quad) << 7) + ct * 16 + m) * 8);
      acc1[0][ct] = __builtin_amdgcn_mfma_f32_16x16x32_bf16(aK0[lk], bv, acc1[0][ct], 0, 0, 0);
      acc1[1][ct] = __builtin_amdgcn_mfma_f32_16x16x32_bf16(aK1[lk], bv, acc1[1][ct], 0, 0, 0);
    }
  }

  // ---- layer 2 per subtile: two 64-col phases; Yt rows wave-private ----
  #pragma unroll 1
  for (int s = 0; s < 2; s++){
    f32x4 acc2[4];
    #pragma unroll
    for (int ct = 0; ct < 4; ct++) acc2[ct] = z4;
    #pragma unroll 1
    for (int ph = 0; ph < 2; ph++){
      #pragma unroll
      for (int c = 0; c < 4; c++){
        int ct = ph * 4 + c;
        #pragma unroll
        for (int i = 0; i < 4; i++){
          float v = acc1[s][ct][i] + b1l[ct * 16 + m];
          v = v > 0.f ? v : 0.f;
          Yt[(w * 16 + quad * 4 + i) * 72 + c * 16 + m] = f2b(v);
        }
      }
      #pragma unroll
      for (int lk = 0; lk < 2; lk++){
        int ko = ph * 2 + lk;
        bf16x8 a2 = *(const bf16x8*)(Yt + (w * 16 + m) * 72 + lk * 32 + quad * 8);
        #pragma unroll
        for (int ct = 0; ct < 4; ct++){
          bf16x8 bv = *(const bf16x8*)(w2s + (((ko * 4 + quad) << 6) + ct * 16 + m) * 8);
          acc2[ct] = __builtin_amdgcn_mfma_f32_16x16x32_bf16(a2, bv, acc2[ct], 0, 0, 0);
        }
      }
    }
    // transpose C through Yt (same-wave DS ordering), store full 128B rows at CSR position
    #pragma unroll
    for (int ct = 0; ct < 4; ct++){
      #pragma unroll
      for (int i = 0; i < 4; i++){
        float v = acc2[ct][i] + b2l[ct * 16 + m];
        Yt[(w * 16 + quad * 4 + i) * 72 + ct * 16 + m] = f2b(v);
      }
    }
    int row_l = lane >> 2, seg = lane & 3;
    int p = perm[ebase + s * 16 + row_l];
    const uint4* tp = (const uint4*)(Yt + (w * 16 + row_l) * 72 + seg * 16);
    uint4 x0 = tp[0], x1 = tp[1];
    uint4* gp = (uint4*)(msg + (((size_t)b * Ee + p) << 6) + seg * 16);
    gp[0] = x0; gp[1] = x1;
  }
}

// ---------------- node MLP: sequential CSR gather (msg pre-sorted by sink) ----------------
__global__ __launch_bounds__(256) void node_kernel(
  float* __restrict__ sf, u16* __restrict__ sbm,
  const u16* __restrict__ msg, const int* __restrict__ rowp,
  const u16* __restrict__ w1s, const u16* __restrict__ w2s,
  const float* __restrict__ b1f, const float* __restrict__ b2f2)
{
  __shared__ __align__(16) u16 ninp[64 * 200];
  __shared__ __align__(16) u16 Yt[64 * 136];
  __shared__ float b1l[128];
  __shared__ float b2l[128];
  int b = (blockIdx.x & 7) >> 1;
  int nt = ((blockIdx.x >> 3) << 1) + (blockIdx.x & 1);
  if (nt >= 157) return;                       // uniform per block
  int n0 = nt * 64;
  int tid = threadIdx.x;
  if (tid < 128) b1l[tid] = b1f[tid];
  else b2l[tid - 128] = b2f2[tid - 128];

  {
    int nl = tid >> 2, part = tid & 3;
    int n = n0 + nl;
    float acc[16];
    #pragma unroll
    for (int i = 0; i < 16; i++) acc[i] = 0.f;
    if (n < Nn){
      int r0 = rowp[n], r1 = rowp[n + 1];
      const u16* mb = msg + (((size_t)b * Ee) << 6) + part * 16;
      for (int r = r0; r < r1; r++){
        const uint4* mp = (const uint4*)(mb + ((size_t)r << 6));
        uint4 p0 = mp[0], p1 = mp[1];
        acc2bf(acc[0], acc[1], p0.x);  acc2bf(acc[2], acc[3], p0.y);
        acc2bf(acc[4], acc[5], p0.z);  acc2bf(acc[6], acc[7], p0.w);
        acc2bf(acc[8], acc[9], p1.x);  acc2bf(acc[10], acc[11], p1.y);
        acc2bf(acc[12], acc[13], p1.z); acc2bf(acc[14], acc[15], p1.w);
      }
    }
    union { u16 h[16]; uint4 v[2]; } tb;
    #pragma unroll
    for (int i = 0; i < 16; i++) tb.h[i] = f2b(acc[i]);
    *(uint4*)(ninp + nl * 200 + part * 16) = tb.v[0];
    *(uint4*)(ninp + nl * 200 + part * 16 + 8) = tb.v[1];
    uint4* dp = (uint4*)(ninp + nl * 200 + 64 + part * 32);
    if (n < Nn){
      const uint4* sp = (const uint4*)(sbm + (((size_t)b * Nn + n) << 7) + part * 32);
      #pragma unroll
      for (int i = 0; i < 4; i++) dp[i] = sp[i];
    } else {
      uint4 zz = {0, 0, 0, 0};
      #pragma unroll
      for (int i = 0; i < 4; i++) dp[i] = zz;
    }
  }
  __syncthreads();

  int w = tid >> 6, lane = tid & 63, m = lane & 15, quad = lane >> 4;
  const f32x4 z4 = {0.f, 0.f, 0.f, 0.f};
  f32x4 acc1[8];
  #pragma unroll
  for (int ct = 0; ct < 8; ct++) acc1[ct] = z4;
  #pragma unroll 1
  for (int ks = 0; ks < 6; ks++){
    bf16x8 a = *(const bf16x8*)(ninp + (w * 16 + m) * 200 + ks * 32 + quad * 8);
    #pragma unroll
    for (int ct = 0; ct < 8; ct++){
      bf16x8 bv = *(const bf16x8*)(w1s + (((ks * 4 + quad) << 7) + ct * 16 + m) * 8);
      acc1[ct] = __builtin_amdgcn_mfma_f32_16x16x32_bf16(a, bv, acc1[ct], 0, 0, 0);
    }
  }
  #pragma unroll
  for (int ct = 0; ct < 8; ct++){
    #pragma unroll
    for (int i = 0; i < 4; i++){
      float v = acc1[ct][i] + b1l[ct * 16 + m];
      v = v > 0.f ? v : 0.f;
      Yt[(w * 16 + quad * 4 + i) * 136 + ct * 16 + m] = f2b(v);
    }
  }
  f32x4 acc2[8];
  #pragma unroll
  for (int ct = 0; ct < 8; ct++) acc2[ct] = z4;
  #pragma unroll 1
  for (int ko = 0; ko < 4; ko++){
    bf16x8 a2 = *(const bf16x8*)(Yt + (w * 16 + m) * 136 + ko * 32 + quad * 8);
    #pragma unroll
    for (int ct = 0; ct < 8; ct++){
      bf16x8 bv = *(const bf16x8*)(w2s + (((ko * 4 + quad) << 7) + ct * 16 + m) * 8);
      acc2[ct] = __builtin_amdgcn_mfma_f32_16x16x32_bf16(a2, bv, acc2[ct], 0, 0, 0);
    }
  }
  #pragma unroll
  for (int ct = 0; ct < 8; ct++){
    int u = ct * 16 + m;
    if (u < 126){
      #pragma unroll
      for (int i = 0; i < 4; i++){
        int n = n0 + w * 16 + quad * 4 + i;
        if (n < Nn){
          size_t idx = (((size_t)b * Nn + n) << 7) + 2 + u;
          float v = sf[idx] + acc2[ct][i] + b2l[u];
          sf[idx] = v;
          sbm[idx] = f2b(v);
        }
      }
    }
  }
}

// ---------------- extraction: MFMA GEMM ----------------
__global__ void swz_attn_kernel(const void* __restrict__ attn, const int* __restrict__ flag,
                                u16* __restrict__ aswz)
{
  int f = *flag;
  const long total = (long)Bx * 16 * KG * 128;
  for (long i = (long)blockIdx.x * blockDim.x + threadIdx.x; i < total; i += (long)gridDim.x * blockDim.x){
    int mj = (int)(i & 127); long r = i >> 7;
    int kg = (int)(r % KG); long r2 = r / KG;
    int qr = (int)(r2 & 15); int b = (int)(r2 >> 4);
    int mm = mj >> 3, j = mj & 7;
    int n = kg * 8 + j, q = qr * 16 + mm;
    float v = (kg < 1250) ? ldin(attn, ((long)(b * Qq + q)) * Nn + n, f) : 0.f;
    aswz[i] = f2b(v);
  }
}
__global__ void swz_s_kernel(const u16* __restrict__ sbm, u16* __restrict__ sswz)
{
  const long total = (long)Bx * KG * 128;
  for (long i = (long)blockIdx.x * blockDim.x + threadIdx.x; i < total; i += (long)gridDim.x * blockDim.x){
    int d = (int)(i & 127); long r = i >> 7;
    int kg = (int)(r % KG); int b = (int)(r / KG);
    union { u16 h[8]; uint4 v[2]; } t;
    if (kg < 1250){
      #pragma unroll
      for (int j = 0; j < 8; j++)
        t.h[j] = sbm[(((size_t)b * Nn + kg * 8 + j) << 7) + d];
    } else {
      #pragma unroll
      for (int j = 0; j < 8; j++) t.h[j] = 0;
    }
    *(uint4*)(sswz + i * 8) = t.v[0];
    *(uint4*)(sswz + i * 8 + 8) = t.v[1];
  }
}
__global__ __launch_bounds__(256) void extract2_kernel(
  const u16* __restrict__ aswz, const u16* __restrict__ sswz, float* __restrict__ part)
{
  int blk = blockIdx.x;
  int kc = blk & 15, qt = (blk >> 4) & 3, b = blk >> 6;
  int tid = threadIdx.x, w = tid >> 6, lane = tid & 63, m = lane & 15, quad = lane >> 4;
  int qr = qt * 4 + w, q0 = qr * 16;
  int kg0 = kc * 80;
  int nsteps = (kc == 15) ? 13 : 20;
  const u16* abase = aswz + ((size_t)(b * 16 + qr)) * KG * 128;
  const u16* sbase = sswz + ((size_t)b) * KG * 1024;
  f32x4 acc[8];
  const f32x4 z4 = {0.f, 0.f, 0.f, 0.f};
  #pragma unroll
  for (int ct = 0; ct < 8; ct++) acc[ct] = z4;
  #pragma unroll 1
  for (int t = 0; t < nsteps; t++){
    int kg = kg0 + t * 4 + quad;
    bf16x8 a = *(const bf16x8*)(abase + (size_t)kg * 128 + m * 8);
    #pragma unroll
    for (int ct = 0; ct < 8; ct++){
      bf16x8 bv = *(const bf16x8*)(sbase + ((size_t)kg * 128 + ct * 16 + m) * 8);
      acc[ct] = __builtin_amdgcn_mfma_f32_16x16x32_bf16(a, bv, acc[ct], 0, 0, 0);
    }
  }
  #pragma unroll
  for (int ct = 0; ct < 8; ct++){
    #pragma unroll
    for (int i = 0; i < 4; i++)
      part[(((size_t)(kc * 4 + b)) * Qq + q0 + quad * 4 + i) * 128 + ct * 16 + m] = acc[ct][i];
  }
}

// ---------------- finalize: out = [poses | sum(16 partials)] ----------------
__global__ void final_kernel(const void* __restrict__ poses, const int* __restrict__ flag,
                             const float* __restrict__ part, void* __restrict__ out)
{
  int f = *flag;
  const long total = (long)Bx * Qq * (Pp + Dd);
  for (long idx = (long)blockIdx.x * blockDim.x + threadIdx.x; idx < total; idx += (long)gridDim.x * blockDim.x){
    int j = (int)(idx % (Pp + Dd));
    long bq = idx / (Pp + Dd);
    float v;
    if (j < Pp){
      v = ldin(poses, bq * Pp + j, f);
    } else {
      int dd = j - Pp;
      int b = (int)(bq >> 8), q = (int)(bq & 255);
      v = 0.f;
      #pragma unroll
      for (int kc = 0; kc < 16; kc++)
        v += part[(((size_t)(kc * 4 + b) * Qq + q) << 7) + dd];
    }
    if (f) ((u16*)out)[idx] = f2b(v);
    else ((float*)out)[idx] = v;
  }
}

extern "C" void kernel_launch(void* const* d_in, const int* in_sizes, int n_in,
                              void* d_out, int out_size, void* d_ws, size_t ws_size,
                              hipStream_t stream)
{
  const void* in_states = d_in[0];
  const void* in_poses  = d_in[1];
  const void* in_attn   = d_in[2];
  const int*  in_src    = (const int*)d_in[3];
  const int*  in_snk    = (const int*)d_in[4];
  const void* in_w1e = d_in[5];  const void* in_b1e = d_in[6];
  const void* in_w2e = d_in[7];  const void* in_b2e = d_in[8];
  const void* in_w1n = d_in[9];  const void* in_b1n = d_in[10];
  const void* in_w2n = d_in[11]; const void* in_b2n = d_in[12];

  char* ws = (char*)d_ws;
  size_t off = 0;
  auto alloc = [&](size_t bytes){ size_t o = off; off = (off + bytes + 255) & ~(size_t)255; return o; };
  size_t o_sf   = alloc((size_t)Bx * Nn * Dd * 4);
  size_t o_sb   = alloc((size_t)Bx * Nn * Dd * 2);
  size_t o_rowp = alloc((size_t)(Nn + 1) * 4);
  size_t o_rcnt = alloc((size_t)Nn * 4);
  size_t o_perm = alloc((size_t)Ee * 4);
  size_t o_w1e  = alloc(32768 * 2);
  size_t o_w2e  = alloc(8192 * 2);
  size_t o_w1n  = alloc(24576 * 2);
  size_t o_w2n  = alloc(16384 * 2);
  size_t o_b1e  = alloc(128 * 4);
  size_t o_b2e  = alloc(64 * 4);
  size_t o_b1n  = alloc(128 * 4);
  size_t o_b2n  = alloc(128 * 4);
  size_t o_flag = alloc(4);

  size_t msgPerB = (size_t)Ee * Mm * 2;            // 20.5 MB
  size_t aswzB = (size_t)Bx * 16 * KG * 128 * 2;   // 20.5 MB
  size_t sswzB = (size_t)Bx * KG * 128 * 8 * 2;    // 10.3 MB
  size_t partB = (size_t)16 * Bx * Qq * Dd * 4;    // 8.4 MB
  size_t swzTot = ((aswzB + 255) & ~(size_t)255) + ((sswzB + 255) & ~(size_t)255) + partB;
  size_t region = 4 * msgPerB;
  if (region < swzTot) region = swzTot;
  size_t o_msg = alloc(region);

  float* sf    = (float*)(ws + o_sf);
  u16*   sbm   = (u16*)(ws + o_sb);
  int*   rowp  = (int*)(ws + o_rowp);
  int*   rcnt  = (int*)(ws + o_rcnt);
  int*   perm  = (int*)(ws + o_perm);
  u16*   w1e_s = (u16*)(ws + o_w1e);
  u16*   w2e_s = (u16*)(ws + o_w2e);
  u16*   w1n_s = (u16*)(ws + o_w1n);
  u16*   w2n_s = (u16*)(ws + o_w2n);
  float* b1e_f = (float*)(ws + o_b1e);
  float* b2e_f = (float*)(ws + o_b2e);
  float* b1n_f = (float*)(ws + o_b1n);
  float* b2n_f = (float*)(ws + o_b2n);
  int*   flag  = (int*)(ws + o_flag);
  u16*   msg   = (u16*)(ws + o_msg);
  u16*   aswz  = (u16*)(ws + o_msg);
  u16*   sswz  = (u16*)(ws + o_msg + ((aswzB + 255) & ~(size_t)255));
  float* part  = (float*)(ws + o_msg + ((aswzB + 255) & ~(size_t)255) + ((sswzB + 255) & ~(size_t)255));

  probe_kernel<<<1, 64, 0, stream>>>(in_states, flag);
  prep_kernel<<<322, 256, 0, stream>>>(in_w1e, in_b1e, in_w2e, in_b2e,
                                       in_w1n, in_b1n, in_w2n, in_b2n, flag,
                                       w1e_s, w2e_s, w1n_s, w2n_s,
                                       b1e_f, b2e_f, b1n_f, b2n_f);
  init_states_kernel<<<1024, 256, 0, stream>>>(in_states, flag, sf, sbm);

  hipMemsetAsync(rcnt, 0, (size_t)Nn * 4, stream);
  count_kernel<<<(Ee + 255) / 256, 256, 0, stream>>>(in_snk, rcnt);
  scan_kernel<<<1, 1024, 0, stream>>>(rcnt, rowp);
  hipMemsetAsync(rcnt, 0, (size_t)Nn * 4, stream);
  fill_kernel<<<(Ee + 255) / 256, 256, 0, stream>>>(in_snk, rowp, rcnt, perm);

  for (int step = 0; step < 3; step++){
    edge_kernel<<<2504, 512, 0, stream>>>(sbm, in_src, in_snk, perm, w1e_s, w2e_s,
                                          b1e_f, b2e_f, msg);
    node_kernel<<<632, 256, 0, stream>>>(sf, sbm, msg, rowp,
                                         w1n_s, w2n_s, b1n_f, b2n_f);
  }
  swz_attn_kernel<<<8192, 256, 0, stream>>>(in_attn, flag, aswz);
  swz_s_kernel<<<2504, 256, 0, stream>>>(sbm, sswz);
  extract2_kernel<<<256, 256, 0, stream>>>(aswz, sswz, part);
  final_kernel<<<540, 256, 0, stream>>>(in_poses, flag, part, d_out);
}

// Round 5
// 1008.478 us; speedup vs baseline: 1.0095x; 1.0095x over previous
//
#include <hip/hip_runtime.h>

// Problem constants (from reference)
#define Bx 4
#define Nn 10000
#define Ee 160000
#define Qq 256
#define Dd 128
#define Mm 64
#define Uu 126
#define Hh 128
#define Pp 7

// N padded to groups of 8 (1250 groups) + 2 pad groups for ragged K-tail
#define KG 1252

typedef unsigned short u16;
typedef __bf16 bf16x8 __attribute__((ext_vector_type(8)));
typedef float f32x4 __attribute__((ext_vector_type(4)));

__device__ __forceinline__ float b2f(u16 h){
  unsigned u = ((unsigned)h) << 16; float f; __builtin_memcpy(&f, &u, 4); return f;
}
__device__ __forceinline__ u16 f2b(float f){
  unsigned u; __builtin_memcpy(&u, &f, 4);
  u = (u + 0x7FFFu + ((u >> 16) & 1u)) >> 16;   // RNE
  return (u16)u;
}
__device__ __forceinline__ float ldin(const void* p, long i, int flag){
  return flag ? b2f(((const u16*)p)[i]) : ((const float*)p)[i];
}
__device__ __forceinline__ void acc2bf(float& a0, float& a1, unsigned v){
  a0 += b2f((u16)(v & 0xffffu));
  a1 += b2f((u16)(v >> 16));
}

// ---------------- dtype probe ----------------
__global__ void probe_kernel(const void* in0, int* flag){
  if (threadIdx.x == 0 && blockIdx.x == 0){
    const u16* p = (const u16*)in0;
    int cnt = 0;
    for (int i = 0; i < 256; i++){
      float a = fabsf(b2f(p[i]));
      if (a > 0.0009765625f && a < 32.0f) cnt++;
    }
    *flag = (cnt >= 240) ? 1 : 0;
  }
}

// ---------------- weight prep: convert + swizzle to MFMA B-frag layout ----------------
__global__ void prep_kernel(const void* w1e, const void* b1e, const void* w2e, const void* b2e,
                            const void* w1n, const void* b1n, const void* w2n, const void* b2n,
                            const int* __restrict__ flag,
                            u16* w1e_s, u16* w2e_s, u16* w1n_s, u16* w2n_s,
                            float* b1e_f, float* b2e_f, float* b1n_f, float* b2n_f)
{
  int f = *flag;
  for (int idx = blockIdx.x * blockDim.x + threadIdx.x; idx < 82368; idx += gridDim.x * blockDim.x){
    if (idx < 32768){                                   // w1e (256,128)
      int k = idx >> 7, h = idx & 127;
      w1e_s[(k >> 3) * 1024 + h * 8 + (k & 7)] = f2b(ldin(w1e, idx, f));
    } else if (idx < 40960){                            // w2e (128,64)
      int i2 = idx - 32768; int k = i2 >> 6, m2 = i2 & 63;
      w2e_s[(k >> 3) * 512 + m2 * 8 + (k & 7)] = f2b(ldin(w2e, i2, f));
    } else if (idx < 65536){                            // w1n (192,128)
      int i2 = idx - 40960; int k = i2 >> 7, h = i2 & 127;
      w1n_s[(k >> 3) * 1024 + h * 8 + (k & 7)] = f2b(ldin(w1n, i2, f));
    } else if (idx < 81920){                            // w2n (128,126) padded to 128 cols
      int i2 = idx - 65536; int k = i2 >> 7, u = i2 & 127;
      float v = (u < 126) ? ldin(w2n, (long)k * 126 + u, f) : 0.f;
      w2n_s[(k >> 3) * 1024 + u * 8 + (k & 7)] = f2b(v);
    } else if (idx < 82048){ b1e_f[idx - 81920] = ldin(b1e, idx - 81920, f); }
    else if (idx < 82112){ b2e_f[idx - 82048] = ldin(b2e, idx - 82048, f); }
    else if (idx < 82240){ b1n_f[idx - 82112] = ldin(b1n, idx - 82112, f); }
    else { int j = idx - 82240; b2n_f[j] = (j < 126) ? ldin(b2n, j, f) : 0.f; }
  }
}

// ---------------- init: f32 master states + bf16 mirror ----------------
__global__ void init_states_kernel(const void* in0, const int* __restrict__ flag,
                                   float* __restrict__ sf, u16* __restrict__ sbm)
{
  int f = *flag;
  const long total = (long)Bx * Nn * Dd;
  for (long i = (long)blockIdx.x * blockDim.x + threadIdx.x; i < total; i += (long)gridDim.x * blockDim.x){
    float v = ldin(in0, i, f);
    sf[i] = v; sbm[i] = f2b(v);
  }
}

// ---------------- CSR build ----------------
__global__ void count_kernel(const int* __restrict__ snk, int* __restrict__ cnt){
  int i = blockIdx.x * blockDim.x + threadIdx.x;
  if (i < Ee) atomicAdd(&cnt[snk[i]], 1);
}
__global__ void scan_kernel(const int* __restrict__ cnt, int* __restrict__ rowp){
  __shared__ int tot[1024];
  int t = threadIdx.x;
  int base = t * 10;
  int local[10]; int s = 0;
  #pragma unroll
  for (int i = 0; i < 10; i++){
    int v = (base + i < Nn) ? cnt[base + i] : 0;
    local[i] = s; s += v;
  }
  tot[t] = s;
  __syncthreads();
  for (int o = 1; o < 1024; o <<= 1){
    int v = (t >= o) ? tot[t - o] : 0;
    __syncthreads();
    tot[t] += v;
    __syncthreads();
  }
  int prefix = (t == 0) ? 0 : tot[t - 1];
  #pragma unroll
  for (int i = 0; i < 10; i++)
    if (base + i < Nn) rowp[base + i] = prefix + local[i];
  if (t == 1023) rowp[Nn] = tot[1023];
}
__global__ void fill_kernel(const int* __restrict__ snk, const int* __restrict__ rowp,
                            int* __restrict__ cnt, int* __restrict__ eidx){
  int i = blockIdx.x * blockDim.x + threadIdx.x;
  if (i < Ee){
    int s = snk[i];
    int p = rowp[s] + atomicAdd(&cnt[s], 1);
    eidx[p] = i;
  }
}

// ---------------- edge MLP v5 ----------------
// 256-edge tiles, 2 M-subtiles/wave (each LDS B-frag feeds 2 MFMAs), XCD-affine
// batch mapping, register-prefetched A-frags per K-half.
// CRITICAL (R2/R4 lesson): msg stores must be CONTIGUOUS per wave instruction —
// 16 sequential edge rows = 2KB contiguous. Scattered rows -> 13x write RMW blowup.
__global__ __launch_bounds__(512) void edge_kernel(
  const u16* __restrict__ sbm, const int* __restrict__ src, const int* __restrict__ snk,
  const u16* __restrict__ w1s, const u16* __restrict__ w2s,
  const float* __restrict__ b1f, const float* __restrict__ b2f2,
  u16* __restrict__ msg)
{
  __shared__ __align__(16) u16 w1h[16384];     // 32KB: one K-half of w1e, swizzled
  __shared__ __align__(16) u16 Yt[128 * 72];   // 18KB: hidden phase / store transpose
  __shared__ float b1l[128];
  __shared__ float b2l[64];
  int tid = threadIdx.x;
  if (tid < 128) b1l[tid] = b1f[tid];
  else if (tid < 192) b2l[tid - 128] = b2f2[tid - 128];

  // blockIdx % 8 -> XCD; batch pinned to an XCD pair. 2504 blocks; tile<625 guard.
  int b = (blockIdx.x & 7) >> 1;
  int tile = ((blockIdx.x >> 3) << 1) + (blockIdx.x & 1);
  if (tile >= 625) return;                     // uniform per block; before any barrier
  int e0 = tile * 256;
  int w = tid >> 6, lane = tid & 63, m = lane & 15, quad = lane >> 4;
  int ebase = e0 + w * 32;
  int eA = ebase + m, eB = ebase + 16 + m;
  int src0 = src[eA], src1 = src[eB];
  int snk0 = snk[eA], snk1 = snk[eB];
  const u16* sbase = sbm + (((size_t)b * Nn) << 7);

  // prefetch src-rows (hide gather latency under half-0 staging)
  bf16x8 aS0[4], aS1[4];
  {
    const u16* r0 = sbase + ((size_t)src0 << 7);
    const u16* r1 = sbase + ((size_t)src1 << 7);
    #pragma unroll
    for (int lk = 0; lk < 4; lk++){
      aS0[lk] = *(const bf16x8*)(r0 + lk * 32 + quad * 8);
      aS1[lk] = *(const bf16x8*)(r1 + lk * 32 + quad * 8);
    }
  }

  f32x4 acc1[2][8];
  const f32x4 z4 = {0.f, 0.f, 0.f, 0.f};
  #pragma unroll
  for (int s = 0; s < 2; s++)
    #pragma unroll
    for (int ct = 0; ct < 8; ct++) acc1[s][ct] = z4;

  // ---- layer 1, K-half 0 (src rows) ----
  {
    const uint4* g = (const uint4*)(w1s);
    uint4* l = (uint4*)w1h;
    #pragma unroll
    for (int i = 0; i < 4; i++) l[tid + i * 512] = g[tid + i * 512];
  }
  __syncthreads();
  #pragma unroll
  for (int lk = 0; lk < 4; lk++){
    #pragma unroll
    for (int ct = 0; ct < 8; ct++){
      bf16x8 bv = *(const bf16x8*)(w1h + (((lk * 4 + quad) << 7) + ct * 16 + m) * 8);
      acc1[0][ct] = __builtin_amdgcn_mfma_f32_16x16x32_bf16(aS0[lk], bv, acc1[0][ct], 0, 0, 0);
      acc1[1][ct] = __builtin_amdgcn_mfma_f32_16x16x32_bf16(aS1[lk], bv, acc1[1][ct], 0, 0, 0);
    }
  }
  // prefetch snk-rows (overlaps half-1 staging wait)
  bf16x8 aK0[4], aK1[4];
  {
    const u16* r0 = sbase + ((size_t)snk0 << 7);
    const u16* r1 = sbase + ((size_t)snk1 << 7);
    #pragma unroll
    for (int lk = 0; lk < 4; lk++){
      aK0[lk] = *(const bf16x8*)(r0 + lk * 32 + quad * 8);
      aK1[lk] = *(const bf16x8*)(r1 + lk * 32 + quad * 8);
    }
  }
  __syncthreads();
  // ---- layer 1, K-half 1 (snk rows) ----
  {
    const uint4* g = (const uint4*)(w1s + 16384);
    uint4* l = (uint4*)w1h;
    #pragma unroll
    for (int i = 0; i < 4; i++) l[tid + i * 512] = g[tid + i * 512];
  }
  __syncthreads();
  #pragma unroll
  for (int lk = 0; lk < 4; lk++){
    #pragma unroll
    for (int ct = 0; ct < 8; ct++){
      bf16x8 bv = *(const bf16x8*)(w1h + (((lk * 4 + quad) << 7) + ct * 16 + m) * 8);
      acc1[0][ct] = __builtin_amdgcn_mfma_f32_16x16x32_bf16(aK0[lk], bv, acc1[0][ct], 0, 0, 0);
      acc1[1][ct] = __builtin_amdgcn_mfma_f32_16x16x32_bf16(aK1[lk], bv, acc1[1][ct], 0, 0, 0);
    }
  }

  // ---- layer 2 per subtile: two 64-col phases; Yt rows wave-private ----
  #pragma unroll 1
  for (int s = 0; s < 2; s++){
    f32x4 acc2[4];
    #pragma unroll
    for (int ct = 0; ct < 4; ct++) acc2[ct] = z4;
    #pragma unroll 1
    for (int ph = 0; ph < 2; ph++){
      #pragma unroll
      for (int c = 0; c < 4; c++){
        int ct = ph * 4 + c;
        #pragma unroll
        for (int i = 0; i < 4; i++){
          float v = acc1[s][ct][i] + b1l[ct * 16 + m];
          v = v > 0.f ? v : 0.f;
          Yt[(w * 16 + quad * 4 + i) * 72 + c * 16 + m] = f2b(v);
        }
      }
      #pragma unroll
      for (int lk = 0; lk < 2; lk++){
        int ko = ph * 2 + lk;
        bf16x8 a2 = *(const bf16x8*)(Yt + (w * 16 + m) * 72 + lk * 32 + quad * 8);
        #pragma unroll
        for (int ct = 0; ct < 4; ct++){
          bf16x8 bv = *(const bf16x8*)(w2s + (((ko * 4 + quad) << 6) + ct * 16 + m) * 8);
          acc2[ct] = __builtin_amdgcn_mfma_f32_16x16x32_bf16(a2, bv, acc2[ct], 0, 0, 0);
        }
      }
    }
    // transpose C through Yt (same-wave DS ordering), store 16 SEQUENTIAL rows (2KB contiguous)
    #pragma unroll
    for (int ct = 0; ct < 4; ct++){
      #pragma unroll
      for (int i = 0; i < 4; i++){
        float v = acc2[ct][i] + b2l[ct * 16 + m];
        Yt[(w * 16 + quad * 4 + i) * 72 + ct * 16 + m] = f2b(v);
      }
    }
    int row_l = lane >> 2, seg = lane & 3;
    const uint4* tp = (const uint4*)(Yt + (w * 16 + row_l) * 72 + seg * 16);
    uint4 x0 = tp[0], x1 = tp[1];
    uint4* gp = (uint4*)(msg + (((size_t)b * Ee + ebase + s * 16 + row_l) << 6) + seg * 16);
    gp[0] = x0; gp[1] = x1;
  }
}

// ---------------- node MLP: CSR gather via eidx indirection ----------------
__global__ __launch_bounds__(256) void node_kernel(
  float* __restrict__ sf, u16* __restrict__ sbm,
  const u16* __restrict__ msg, const int* __restrict__ rowp, const int* __restrict__ eidx,
  const u16* __restrict__ w1s, const u16* __restrict__ w2s,
  const float* __restrict__ b1f, const float* __restrict__ b2f2)
{
  __shared__ __align__(16) u16 ninp[64 * 200];
  __shared__ __align__(16) u16 Yt[64 * 136];
  __shared__ float b1l[128];
  __shared__ float b2l[128];
  int b = (blockIdx.x & 7) >> 1;
  int nt = ((blockIdx.x >> 3) << 1) + (blockIdx.x & 1);
  if (nt >= 157) return;                       // uniform per block
  int n0 = nt * 64;
  int tid = threadIdx.x;
  if (tid < 128) b1l[tid] = b1f[tid];
  else b2l[tid - 128] = b2f2[tid - 128];

  {
    int nl = tid >> 2, part = tid & 3;
    int n = n0 + nl;
    float acc[16];
    #pragma unroll
    for (int i = 0; i < 16; i++) acc[i] = 0.f;
    if (n < Nn){
      int r0 = rowp[n], r1 = rowp[n + 1];
      const u16* mb = msg + (((size_t)b * Ee) << 6) + part * 16;
      for (int j = r0; j < r1; j++){
        int e = eidx[j];
        const uint4* mp = (const uint4*)(mb + ((size_t)e << 6));
        uint4 p0 = mp[0], p1 = mp[1];
        acc2bf(acc[0], acc[1], p0.x);  acc2bf(acc[2], acc[3], p0.y);
        acc2bf(acc[4], acc[5], p0.z);  acc2bf(acc[6], acc[7], p0.w);
        acc2bf(acc[8], acc[9], p1.x);  acc2bf(acc[10], acc[11], p1.y);
        acc2bf(acc[12], acc[13], p1.z); acc2bf(acc[14], acc[15], p1.w);
      }
    }
    union { u16 h[16]; uint4 v[2]; } tb;
    #pragma unroll
    for (int i = 0; i < 16; i++) tb.h[i] = f2b(acc[i]);
    *(uint4*)(ninp + nl * 200 + part * 16) = tb.v[0];
    *(uint4*)(ninp + nl * 200 + part * 16 + 8) = tb.v[1];
    uint4* dp = (uint4*)(ninp + nl * 200 + 64 + part * 32);
    if (n < Nn){
      const uint4* sp = (const uint4*)(sbm + (((size_t)b * Nn + n) << 7) + part * 32);
      #pragma unroll
      for (int i = 0; i < 4; i++) dp[i] = sp[i];
    } else {
      uint4 zz = {0, 0, 0, 0};
      #pragma unroll
      for (int i = 0; i < 4; i++) dp[i] = zz;
    }
  }
  __syncthreads();

  int w = tid >> 6, lane = tid & 63, m = lane & 15, quad = lane >> 4;
  const f32x4 z4 = {0.f, 0.f, 0.f, 0.f};
  f32x4 acc1[8];
  #pragma unroll
  for (int ct = 0; ct < 8; ct++) acc1[ct] = z4;
  #pragma unroll 1
  for (int ks = 0; ks < 6; ks++){
    bf16x8 a = *(const bf16x8*)(ninp + (w * 16 + m) * 200 + ks * 32 + quad * 8);
    #pragma unroll
    for (int ct = 0; ct < 8; ct++){
      bf16x8 bv = *(const bf16x8*)(w1s + (((ks * 4 + quad) << 7) + ct * 16 + m) * 8);
      acc1[ct] = __builtin_amdgcn_mfma_f32_16x16x32_bf16(a, bv, acc1[ct], 0, 0, 0);
    }
  }
  #pragma unroll
  for (int ct = 0; ct < 8; ct++){
    #pragma unroll
    for (int i = 0; i < 4; i++){
      float v = acc1[ct][i] + b1l[ct * 16 + m];
      v = v > 0.f ? v : 0.f;
      Yt[(w * 16 + quad * 4 + i) * 136 + ct * 16 + m] = f2b(v);
    }
  }
  f32x4 acc2[8];
  #pragma unroll
  for (int ct = 0; ct < 8; ct++) acc2[ct] = z4;
  #pragma unroll 1
  for (int ko = 0; ko < 4; ko++){
    bf16x8 a2 = *(const bf16x8*)(Yt + (w * 16 + m) * 136 + ko * 32 + quad * 8);
    #pragma unroll
    for (int ct = 0; ct < 8; ct++){
      bf16x8 bv = *(const bf16x8*)(w2s + (((ko * 4 + quad) << 7) + ct * 16 + m) * 8);
      acc2[ct] = __builtin_amdgcn_mfma_f32_16x16x32_bf16(a2, bv, acc2[ct], 0, 0, 0);
    }
  }
  #pragma unroll
  for (int ct = 0; ct < 8; ct++){
    int u = ct * 16 + m;
    if (u < 126){
      #pragma unroll
      for (int i = 0; i < 4; i++){
        int n = n0 + w * 16 + quad * 4 + i;
        if (n < Nn){
          size_t idx = (((size_t)b * Nn + n) << 7) + 2 + u;
          float v = sf[idx] + acc2[ct][i] + b2l[u];
          sf[idx] = v;
          sbm[idx] = f2b(v);
        }
      }
    }
  }
}

// ---------------- extraction: MFMA GEMM ----------------
__global__ void swz_attn_kernel(const void* __restrict__ attn, const int* __restrict__ flag,
                                u16* __restrict__ aswz)
{
  int f = *flag;
  const long total = (long)Bx * 16 * KG * 128;
  for (long i = (long)blockIdx.x * blockDim.x + threadIdx.x; i < total; i += (long)gridDim.x * blockDim.x){
    int mj = (int)(i & 127); long r = i >> 7;
    int kg = (int)(r % KG); long r2 = r / KG;
    int qr = (int)(r2 & 15); int b = (int)(r2 >> 4);
    int mm = mj >> 3, j = mj & 7;
    int n = kg * 8 + j, q = qr * 16 + mm;
    float v = (kg < 1250) ? ldin(attn, ((long)(b * Qq + q)) * Nn + n, f) : 0.f;
    aswz[i] = f2b(v);
  }
}
__global__ void swz_s_kernel(const u16* __restrict__ sbm, u16* __restrict__ sswz)
{
  const long total = (long)Bx * KG * 128;
  for (long i = (long)blockIdx.x * blockDim.x + threadIdx.x; i < total; i += (long)gridDim.x * blockDim.x){
    int d = (int)(i & 127); long r = i >> 7;
    int kg = (int)(r % KG); int b = (int)(r / KG);
    union { u16 h[8]; uint4 v[2]; } t;
    if (kg < 1250){
      #pragma unroll
      for (int j = 0; j < 8; j++)
        t.h[j] = sbm[(((size_t)b * Nn + kg * 8 + j) << 7) + d];
    } else {
      #pragma unroll
      for (int j = 0; j < 8; j++) t.h[j] = 0;
    }
    *(uint4*)(sswz + i * 8) = t.v[0];
    *(uint4*)(sswz + i * 8 + 8) = t.v[1];
  }
}
__global__ __launch_bounds__(256) void extract2_kernel(
  const u16* __restrict__ aswz, const u16* __restrict__ sswz, float* __restrict__ part)
{
  int blk = blockIdx.x;
  int kc = blk & 15, qt = (blk >> 4) & 3, b = blk >> 6;
  int tid = threadIdx.x, w = tid >> 6, lane = tid & 63, m = lane & 15, quad = lane >> 4;
  int qr = qt * 4 + w, q0 = qr * 16;
  int kg0 = kc * 80;
  int nsteps = (kc == 15) ? 13 : 20;
  const u16* abase = aswz + ((size_t)(b * 16 + qr)) * KG * 128;
  const u16* sbase = sswz + ((size_t)b) * KG * 1024;
  f32x4 acc[8];
  const f32x4 z4 = {0.f, 0.f, 0.f, 0.f};
  #pragma unroll
  for (int ct = 0; ct < 8; ct++) acc[ct] = z4;
  #pragma unroll 1
  for (int t = 0; t < nsteps; t++){
    int kg = kg0 + t * 4 + quad;
    bf16x8 a = *(const bf16x8*)(abase + (size_t)kg * 128 + m * 8);
    #pragma unroll
    for (int ct = 0; ct < 8; ct++){
      bf16x8 bv = *(const bf16x8*)(sbase + ((size_t)kg * 128 + ct * 16 + m) * 8);
      acc[ct] = __builtin_amdgcn_mfma_f32_16x16x32_bf16(a, bv, acc[ct], 0, 0, 0);
    }
  }
  #pragma unroll
  for (int ct = 0; ct < 8; ct++){
    #pragma unroll
    for (int i = 0; i < 4; i++)
      part[(((size_t)(kc * 4 + b)) * Qq + q0 + quad * 4 + i) * 128 + ct * 16 + m] = acc[ct][i];
  }
}

// ---------------- finalize: out = [poses | sum(16 partials)] ----------------
__global__ void final_kernel(const void* __restrict__ poses, const int* __restrict__ flag,
                             const float* __restrict__ part, void* __restrict__ out)
{
  int f = *flag;
  const long total = (long)Bx * Qq * (Pp + Dd);
  for (long idx = (long)blockIdx.x * blockDim.x + threadIdx.x; idx < total; idx += (long)gridDim.x * blockDim.x){
    int j = (int)(idx % (Pp + Dd));
    long bq = idx / (Pp + Dd);
    float v;
    if (j < Pp){
      v = ldin(poses, bq * Pp + j, f);
    } else {
      int dd = j - Pp;
      int b = (int)(bq >> 8), q = (int)(bq & 255);
      v = 0.f;
      #pragma unroll
      for (int kc = 0; kc < 16; kc++)
        v += part[(((size_t)(kc * 4 + b) * Qq + q) << 7) + dd];
    }
    if (f) ((u16*)out)[idx] = f2b(v);
    else ((float*)out)[idx] = v;
  }
}

extern "C" void kernel_launch(void* const* d_in, const int* in_sizes, int n_in,
                              void* d_out, int out_size, void* d_ws, size_t ws_size,
                              hipStream_t stream)
{
  const void* in_states = d_in[0];
  const void* in_poses  = d_in[1];
  const void* in_attn   = d_in[2];
  const int*  in_src    = (const int*)d_in[3];
  const int*  in_snk    = (const int*)d_in[4];
  const void* in_w1e = d_in[5];  const void* in_b1e = d_in[6];
  const void* in_w2e = d_in[7];  const void* in_b2e = d_in[8];
  const void* in_w1n = d_in[9];  const void* in_b1n = d_in[10];
  const void* in_w2n = d_in[11]; const void* in_b2n = d_in[12];

  char* ws = (char*)d_ws;
  size_t off = 0;
  auto alloc = [&](size_t bytes){ size_t o = off; off = (off + bytes + 255) & ~(size_t)255; return o; };
  size_t o_sf   = alloc((size_t)Bx * Nn * Dd * 4);
  size_t o_sb   = alloc((size_t)Bx * Nn * Dd * 2);
  size_t o_rowp = alloc((size_t)(Nn + 1) * 4);
  size_t o_rcnt = alloc((size_t)Nn * 4);
  size_t o_eidx = alloc((size_t)Ee * 4);
  size_t o_w1e  = alloc(32768 * 2);
  size_t o_w2e  = alloc(8192 * 2);
  size_t o_w1n  = alloc(24576 * 2);
  size_t o_w2n  = alloc(16384 * 2);
  size_t o_b1e  = alloc(128 * 4);
  size_t o_b2e  = alloc(64 * 4);
  size_t o_b1n  = alloc(128 * 4);
  size_t o_b2n  = alloc(128 * 4);
  size_t o_flag = alloc(4);

  size_t msgPerB = (size_t)Ee * Mm * 2;            // 20.5 MB
  size_t aswzB = (size_t)Bx * 16 * KG * 128 * 2;   // 20.5 MB
  size_t sswzB = (size_t)Bx * KG * 128 * 8 * 2;    // 10.3 MB
  size_t partB = (size_t)16 * Bx * Qq * Dd * 4;    // 8.4 MB
  size_t swzTot = ((aswzB + 255) & ~(size_t)255) + ((sswzB + 255) & ~(size_t)255) + partB;
  size_t region = 4 * msgPerB;
  if (region < swzTot) region = swzTot;
  size_t o_msg = alloc(region);

  float* sf    = (float*)(ws + o_sf);
  u16*   sbm   = (u16*)(ws + o_sb);
  int*   rowp  = (int*)(ws + o_rowp);
  int*   rcnt  = (int*)(ws + o_rcnt);
  int*   eidx  = (int*)(ws + o_eidx);
  u16*   w1e_s = (u16*)(ws + o_w1e);
  u16*   w2e_s = (u16*)(ws + o_w2e);
  u16*   w1n_s = (u16*)(ws + o_w1n);
  u16*   w2n_s = (u16*)(ws + o_w2n);
  float* b1e_f = (float*)(ws + o_b1e);
  float* b2e_f = (float*)(ws + o_b2e);
  float* b1n_f = (float*)(ws + o_b1n);
  float* b2n_f = (float*)(ws + o_b2n);
  int*   flag  = (int*)(ws + o_flag);
  u16*   msg   = (u16*)(ws + o_msg);
  u16*   aswz  = (u16*)(ws + o_msg);
  u16*   sswz  = (u16*)(ws + o_msg + ((aswzB + 255) & ~(size_t)255));
  float* part  = (float*)(ws + o_msg + ((aswzB + 255) & ~(size_t)255) + ((sswzB + 255) & ~(size_t)255));

  probe_kernel<<<1, 64, 0, stream>>>(in_states, flag);
  prep_kernel<<<322, 256, 0, stream>>>(in_w1e, in_b1e, in_w2e, in_b2e,
                                       in_w1n, in_b1n, in_w2n, in_b2n, flag,
                                       w1e_s, w2e_s, w1n_s, w2n_s,
                                       b1e_f, b2e_f, b1n_f, b2n_f);
  init_states_kernel<<<1024, 256, 0, stream>>>(in_states, flag, sf, sbm);

  hipMemsetAsync(rcnt, 0, (size_t)Nn * 4, stream);
  count_kernel<<<(Ee + 255) / 256, 256, 0, stream>>>(in_snk, rcnt);
  scan_kernel<<<1, 1024, 0, stream>>>(rcnt, rowp);
  hipMemsetAsync(rcnt, 0, (size_t)Nn * 4, stream);
  fill_kernel<<<(Ee + 255) / 256, 256, 0, stream>>>(in_snk, rowp, rcnt, eidx);

  for (int step = 0; step < 3; step++){
    edge_kernel<<<2504, 512, 0, stream>>>(sbm, in_src, in_snk, w1e_s, w2e_s,
                                          b1e_f, b2e_f, msg);
    node_kernel<<<632, 256, 0, stream>>>(sf, sbm, msg, rowp, eidx,
                                         w1n_s, w2n_s, b1n_f, b2n_f);
  }
  swz_attn_kernel<<<8192, 256, 0, stream>>>(in_attn, flag, aswz);
  swz_s_kernel<<<2504, 256, 0, stream>>>(sbm, sswz);
  extract2_kernel<<<256, 256, 0, stream>>>(aswz, sswz, part);
  final_kernel<<<540, 256, 0, stream>>>(in_poses, flag, part, d_out);
}

// Round 6
// 1004.123 us; speedup vs baseline: 1.0138x; 1.0043x over previous
//
#include <hip/hip_runtime.h>

// Problem constants (from reference)
#define Bx 4
#define Nn 10000
#define Ee 160000
#define Qq 256
#define Dd 128
#define Mm 64
#define Uu 126
#define Hh 128
#define Pp 7

// N padded to groups of 8 (1250 groups) + 2 pad groups for ragged K-tail
#define KG 1252

typedef unsigned short u16;
typedef __bf16 bf16x8 __attribute__((ext_vector_type(8)));
typedef float f32x4 __attribute__((ext_vector_type(4)));

__device__ __forceinline__ float b2f(u16 h){
  unsigned u = ((unsigned)h) << 16; float f; __builtin_memcpy(&f, &u, 4); return f;
}
__device__ __forceinline__ u16 f2b(float f){
  unsigned u; __builtin_memcpy(&u, &f, 4);
  u = (u + 0x7FFFu + ((u >> 16) & 1u)) >> 16;   // RNE
  return (u16)u;
}
__device__ __forceinline__ float ldin(const void* p, long i, int flag){
  return flag ? b2f(((const u16*)p)[i]) : ((const float*)p)[i];
}
__device__ __forceinline__ void acc2bf(float& a0, float& a1, unsigned v){
  a0 += b2f((u16)(v & 0xffffu));
  a1 += b2f((u16)(v >> 16));
}

// ---------------- dtype probe ----------------
__global__ void probe_kernel(const void* in0, int* flag){
  if (threadIdx.x == 0 && blockIdx.x == 0){
    const u16* p = (const u16*)in0;
    int cnt = 0;
    for (int i = 0; i < 256; i++){
      float a = fabsf(b2f(p[i]));
      if (a > 0.0009765625f && a < 32.0f) cnt++;
    }
    *flag = (cnt >= 240) ? 1 : 0;
  }
}

// ---------------- weight prep: convert + swizzle to MFMA B-frag layout ----------------
__global__ void prep_kernel(const void* w1e, const void* b1e, const void* w2e, const void* b2e,
                            const void* w1n, const void* b1n, const void* w2n, const void* b2n,
                            const int* __restrict__ flag,
                            u16* w1e_s, u16* w2e_s, u16* w1n_s, u16* w2n_s,
                            float* b1e_f, float* b2e_f, float* b1n_f, float* b2n_f)
{
  int f = *flag;
  for (int idx = blockIdx.x * blockDim.x + threadIdx.x; idx < 82368; idx += gridDim.x * blockDim.x){
    if (idx < 32768){                                   // w1e (256,128)
      int k = idx >> 7, h = idx & 127;
      w1e_s[(k >> 3) * 1024 + h * 8 + (k & 7)] = f2b(ldin(w1e, idx, f));
    } else if (idx < 40960){                            // w2e (128,64)
      int i2 = idx - 32768; int k = i2 >> 6, m2 = i2 & 63;
      w2e_s[(k >> 3) * 512 + m2 * 8 + (k & 7)] = f2b(ldin(w2e, i2, f));
    } else if (idx < 65536){                            // w1n (192,128)
      int i2 = idx - 40960; int k = i2 >> 7, h = i2 & 127;
      w1n_s[(k >> 3) * 1024 + h * 8 + (k & 7)] = f2b(ldin(w1n, i2, f));
    } else if (idx < 81920){                            // w2n (128,126) padded to 128 cols
      int i2 = idx - 65536; int k = i2 >> 7, u = i2 & 127;
      float v = (u < 126) ? ldin(w2n, (long)k * 126 + u, f) : 0.f;
      w2n_s[(k >> 3) * 1024 + u * 8 + (k & 7)] = f2b(v);
    } else if (idx < 82048){ b1e_f[idx - 81920] = ldin(b1e, idx - 81920, f); }
    else if (idx < 82112){ b2e_f[idx - 82048] = ldin(b2e, idx - 82048, f); }
    else if (idx < 82240){ b1n_f[idx - 82112] = ldin(b1n, idx - 82112, f); }
    else { int j = idx - 82240; b2n_f[j] = (j < 126) ? ldin(b2n, j, f) : 0.f; }
  }
}

// ---------------- init: f32 master states + bf16 mirror ----------------
__global__ void init_states_kernel(const void* in0, const int* __restrict__ flag,
                                   float* __restrict__ sf, u16* __restrict__ sbm)
{
  int f = *flag;
  const long total = (long)Bx * Nn * Dd;
  for (long i = (long)blockIdx.x * blockDim.x + threadIdx.x; i < total; i += (long)gridDim.x * blockDim.x){
    float v = ldin(in0, i, f);
    sf[i] = v; sbm[i] = f2b(v);
  }
}

// ---------------- CSR build ----------------
__global__ void count_kernel(const int* __restrict__ snk, int* __restrict__ cnt){
  int i = blockIdx.x * blockDim.x + threadIdx.x;
  if (i < Ee) atomicAdd(&cnt[snk[i]], 1);
}
__global__ void scan_kernel(const int* __restrict__ cnt, int* __restrict__ rowp){
  __shared__ int tot[1024];
  int t = threadIdx.x;
  int base = t * 10;
  int local[10]; int s = 0;
  #pragma unroll
  for (int i = 0; i < 10; i++){
    int v = (base + i < Nn) ? cnt[base + i] : 0;
    local[i] = s; s += v;
  }
  tot[t] = s;
  __syncthreads();
  for (int o = 1; o < 1024; o <<= 1){
    int v = (t >= o) ? tot[t - o] : 0;
    __syncthreads();
    tot[t] += v;
    __syncthreads();
  }
  int prefix = (t == 0) ? 0 : tot[t - 1];
  #pragma unroll
  for (int i = 0; i < 10; i++)
    if (base + i < Nn) rowp[base + i] = prefix + local[i];
  if (t == 1023) rowp[Nn] = tot[1023];
}
__global__ void fill_kernel(const int* __restrict__ snk, const int* __restrict__ rowp,
                            int* __restrict__ cnt, int* __restrict__ eidx){
  int i = blockIdx.x * blockDim.x + threadIdx.x;
  if (i < Ee){
    int s = snk[i];
    int p = rowp[s] + atomicAdd(&cnt[s], 1);
    eidx[p] = i;
  }
}

// ---------------- edge MLP v6 ----------------
// 2 M-subtiles/wave (each LDS B-frag feeds 2 MFMAs — halves the dominant LDS
// operand traffic). 256-thread blocks (4 waves x 32 edges = 128 edges/block) and
// __launch_bounds__(256,3): VGPR cap ~170 >= ~130 demand. R2/R4/R5 lesson: with
// 512-thr blocks the backend capped VGPRs at 64 via its LDS-occupancy heuristic
// and spilled the 2-subtile accumulators to scratch -> 1.04GB HBM writes.
__global__ __launch_bounds__(256, 3) void edge_kernel(
  const u16* __restrict__ sbm, const int* __restrict__ src, const int* __restrict__ snk,
  const u16* __restrict__ w1s, const u16* __restrict__ w2s,
  const float* __restrict__ b1f, const float* __restrict__ b2f2,
  u16* __restrict__ msg)
{
  __shared__ __align__(16) u16 w1h[16384];     // 32KB: one K-half of w1e, swizzled
  __shared__ __align__(16) u16 Yt[64 * 72];    // 9KB: hidden phase / store transpose
  __shared__ float b1l[128];
  __shared__ float b2l[64];
  int tid = threadIdx.x;
  if (tid < 128) b1l[tid] = b1f[tid];
  else if (tid < 192) b2l[tid - 128] = b2f2[tid - 128];

  // blockIdx % 8 -> XCD; batch pinned to an XCD pair. 5000 = 1250 tiles x 4 batches.
  int b = (blockIdx.x & 7) >> 1;
  int tile = ((blockIdx.x >> 3) << 1) + (blockIdx.x & 1);   // 0..1249
  int e0 = tile * 128;
  int w = tid >> 6, lane = tid & 63, m = lane & 15, quad = lane >> 4;
  int ebase = e0 + w * 32;
  int eA = ebase + m, eB = ebase + 16 + m;
  int src0 = src[eA], src1 = src[eB];
  int snk0 = snk[eA], snk1 = snk[eB];
  const u16* sbase = sbm + (((size_t)b * Nn) << 7);

  // prefetch src-rows (gather latency hides under half-0 staging)
  bf16x8 aS0[4], aS1[4];
  {
    const u16* r0 = sbase + ((size_t)src0 << 7);
    const u16* r1 = sbase + ((size_t)src1 << 7);
    #pragma unroll
    for (int lk = 0; lk < 4; lk++){
      aS0[lk] = *(const bf16x8*)(r0 + lk * 32 + quad * 8);
      aS1[lk] = *(const bf16x8*)(r1 + lk * 32 + quad * 8);
    }
  }

  f32x4 acc1[2][8];
  const f32x4 z4 = {0.f, 0.f, 0.f, 0.f};
  #pragma unroll
  for (int s = 0; s < 2; s++)
    #pragma unroll
    for (int ct = 0; ct < 8; ct++) acc1[s][ct] = z4;

  // ---- layer 1, K-half 0 (src rows) ----
  {
    const uint4* g = (const uint4*)(w1s);
    uint4* l = (uint4*)w1h;
    #pragma unroll
    for (int i = 0; i < 8; i++) l[tid + i * 256] = g[tid + i * 256];
  }
  __syncthreads();
  #pragma unroll
  for (int lk = 0; lk < 4; lk++){
    #pragma unroll
    for (int ct = 0; ct < 8; ct++){
      bf16x8 bv = *(const bf16x8*)(w1h + (((lk * 4 + quad) << 7) + ct * 16 + m) * 8);
      acc1[0][ct] = __builtin_amdgcn_mfma_f32_16x16x32_bf16(aS0[lk], bv, acc1[0][ct], 0, 0, 0);
      acc1[1][ct] = __builtin_amdgcn_mfma_f32_16x16x32_bf16(aS1[lk], bv, acc1[1][ct], 0, 0, 0);
    }
  }
  // prefetch snk-rows (overlaps half-1 staging wait)
  bf16x8 aK0[4], aK1[4];
  {
    const u16* r0 = sbase + ((size_t)snk0 << 7);
    const u16* r1 = sbase + ((size_t)snk1 << 7);
    #pragma unroll
    for (int lk = 0; lk < 4; lk++){
      aK0[lk] = *(const bf16x8*)(r0 + lk * 32 + quad * 8);
      aK1[lk] = *(const bf16x8*)(r1 + lk * 32 + quad * 8);
    }
  }
  __syncthreads();
  // ---- layer 1, K-half 1 (snk rows) ----
  {
    const uint4* g = (const uint4*)(w1s + 16384);
    uint4* l = (uint4*)w1h;
    #pragma unroll
    for (int i = 0; i < 8; i++) l[tid + i * 256] = g[tid + i * 256];
  }
  __syncthreads();
  #pragma unroll
  for (int lk = 0; lk < 4; lk++){
    #pragma unroll
    for (int ct = 0; ct < 8; ct++){
      bf16x8 bv = *(const bf16x8*)(w1h + (((lk * 4 + quad) << 7) + ct * 16 + m) * 8);
      acc1[0][ct] = __builtin_amdgcn_mfma_f32_16x16x32_bf16(aK0[lk], bv, acc1[0][ct], 0, 0, 0);
      acc1[1][ct] = __builtin_amdgcn_mfma_f32_16x16x32_bf16(aK1[lk], bv, acc1[1][ct], 0, 0, 0);
    }
  }

  // ---- layer 2 per subtile: two 64-col phases; Yt rows wave-private ----
  #pragma unroll 1
  for (int s = 0; s < 2; s++){
    f32x4 acc2[4];
    #pragma unroll
    for (int ct = 0; ct < 4; ct++) acc2[ct] = z4;
    #pragma unroll 1
    for (int ph = 0; ph < 2; ph++){
      #pragma unroll
      for (int c = 0; c < 4; c++){
        int ct = ph * 4 + c;
        #pragma unroll
        for (int i = 0; i < 4; i++){
          float v = acc1[s][ct][i] + b1l[ct * 16 + m];
          v = v > 0.f ? v : 0.f;
          Yt[(w * 16 + quad * 4 + i) * 72 + c * 16 + m] = f2b(v);
        }
      }
      #pragma unroll
      for (int lk = 0; lk < 2; lk++){
        int ko = ph * 2 + lk;
        bf16x8 a2 = *(const bf16x8*)(Yt + (w * 16 + m) * 72 + lk * 32 + quad * 8);
        #pragma unroll
        for (int ct = 0; ct < 4; ct++){
          bf16x8 bv = *(const bf16x8*)(w2s + (((ko * 4 + quad) << 6) + ct * 16 + m) * 8);
          acc2[ct] = __builtin_amdgcn_mfma_f32_16x16x32_bf16(a2, bv, acc2[ct], 0, 0, 0);
        }
      }
    }
    // transpose C through Yt (wave-private), store 16 sequential rows (2KB contiguous)
    #pragma unroll
    for (int ct = 0; ct < 4; ct++){
      #pragma unroll
      for (int i = 0; i < 4; i++){
        float v = acc2[ct][i] + b2l[ct * 16 + m];
        Yt[(w * 16 + quad * 4 + i) * 72 + ct * 16 + m] = f2b(v);
      }
    }
    int row_l = lane >> 2, seg = lane & 3;
    const uint4* tp = (const uint4*)(Yt + (w * 16 + row_l) * 72 + seg * 16);
    uint4 x0 = tp[0], x1 = tp[1];
    uint4* gp = (uint4*)(msg + (((size_t)b * Ee + ebase + s * 16 + row_l) << 6) + seg * 16);
    gp[0] = x0; gp[1] = x1;
  }
}

// ---------------- node MLP: CSR gather via eidx indirection ----------------
__global__ __launch_bounds__(256) void node_kernel(
  float* __restrict__ sf, u16* __restrict__ sbm,
  const u16* __restrict__ msg, const int* __restrict__ rowp, const int* __restrict__ eidx,
  const u16* __restrict__ w1s, const u16* __restrict__ w2s,
  const float* __restrict__ b1f, const float* __restrict__ b2f2)
{
  __shared__ __align__(16) u16 ninp[64 * 200];
  __shared__ __align__(16) u16 Yt[64 * 136];
  __shared__ float b1l[128];
  __shared__ float b2l[128];
  int b = (blockIdx.x & 7) >> 1;
  int nt = ((blockIdx.x >> 3) << 1) + (blockIdx.x & 1);
  if (nt >= 157) return;                       // uniform per block
  int n0 = nt * 64;
  int tid = threadIdx.x;
  if (tid < 128) b1l[tid] = b1f[tid];
  else b2l[tid - 128] = b2f2[tid - 128];

  {
    int nl = tid >> 2, part = tid & 3;
    int n = n0 + nl;
    float acc[16];
    #pragma unroll
    for (int i = 0; i < 16; i++) acc[i] = 0.f;
    if (n < Nn){
      int r0 = rowp[n], r1 = rowp[n + 1];
      const u16* mb = msg + (((size_t)b * Ee) << 6) + part * 16;
      for (int j = r0; j < r1; j++){
        int e = eidx[j];
        const uint4* mp = (const uint4*)(mb + ((size_t)e << 6));
        uint4 p0 = mp[0], p1 = mp[1];
        acc2bf(acc[0], acc[1], p0.x);  acc2bf(acc[2], acc[3], p0.y);
        acc2bf(acc[4], acc[5], p0.z);  acc2bf(acc[6], acc[7], p0.w);
        acc2bf(acc[8], acc[9], p1.x);  acc2bf(acc[10], acc[11], p1.y);
        acc2bf(acc[12], acc[13], p1.z); acc2bf(acc[14], acc[15], p1.w);
      }
    }
    union { u16 h[16]; uint4 v[2]; } tb;
    #pragma unroll
    for (int i = 0; i < 16; i++) tb.h[i] = f2b(acc[i]);
    *(uint4*)(ninp + nl * 200 + part * 16) = tb.v[0];
    *(uint4*)(ninp + nl * 200 + part * 16 + 8) = tb.v[1];
    uint4* dp = (uint4*)(ninp + nl * 200 + 64 + part * 32);
    if (n < Nn){
      const uint4* sp = (const uint4*)(sbm + (((size_t)b * Nn + n) << 7) + part * 32);
      #pragma unroll
      for (int i = 0; i < 4; i++) dp[i] = sp[i];
    } else {
      uint4 zz = {0, 0, 0, 0};
      #pragma unroll
      for (int i = 0; i < 4; i++) dp[i] = zz;
    }
  }
  __syncthreads();

  int w = tid >> 6, lane = tid & 63, m = lane & 15, quad = lane >> 4;
  const f32x4 z4 = {0.f, 0.f, 0.f, 0.f};
  f32x4 acc1[8];
  #pragma unroll
  for (int ct = 0; ct < 8; ct++) acc1[ct] = z4;
  #pragma unroll 1
  for (int ks = 0; ks < 6; ks++){
    bf16x8 a = *(const bf16x8*)(ninp + (w * 16 + m) * 200 + ks * 32 + quad * 8);
    #pragma unroll
    for (int ct = 0; ct < 8; ct++){
      bf16x8 bv = *(const bf16x8*)(w1s + (((ks * 4 + quad) << 7) + ct * 16 + m) * 8);
      acc1[ct] = __builtin_amdgcn_mfma_f32_16x16x32_bf16(a, bv, acc1[ct], 0, 0, 0);
    }
  }
  #pragma unroll
  for (int ct = 0; ct < 8; ct++){
    #pragma unroll
    for (int i = 0; i < 4; i++){
      float v = acc1[ct][i] + b1l[ct * 16 + m];
      v = v > 0.f ? v : 0.f;
      Yt[(w * 16 + quad * 4 + i) * 136 + ct * 16 + m] = f2b(v);
    }
  }
  f32x4 acc2[8];
  #pragma unroll
  for (int ct = 0; ct < 8; ct++) acc2[ct] = z4;
  #pragma unroll 1
  for (int ko = 0; ko < 4; ko++){
    bf16x8 a2 = *(const bf16x8*)(Yt + (w * 16 + m) * 136 + ko * 32 + quad * 8);
    #pragma unroll
    for (int ct = 0; ct < 8; ct++){
      bf16x8 bv = *(const bf16x8*)(w2s + (((ko * 4 + quad) << 7) + ct * 16 + m) * 8);
      acc2[ct] = __builtin_amdgcn_mfma_f32_16x16x32_bf16(a2, bv, acc2[ct], 0, 0, 0);
    }
  }
  #pragma unroll
  for (int ct = 0; ct < 8; ct++){
    int u = ct * 16 + m;
    if (u < 126){
      #pragma unroll
      for (int i = 0; i < 4; i++){
        int n = n0 + w * 16 + quad * 4 + i;
        if (n < Nn){
          size_t idx = (((size_t)b * Nn + n) << 7) + 2 + u;
          float v = sf[idx] + acc2[ct][i] + b2l[u];
          sf[idx] = v;
          sbm[idx] = f2b(v);
        }
      }
    }
  }
}

// ---------------- extraction: MFMA GEMM ----------------
__global__ void swz_attn_kernel(const void* __restrict__ attn, const int* __restrict__ flag,
                                u16* __restrict__ aswz)
{
  int f = *flag;
  const long total = (long)Bx * 16 * KG * 128;
  for (long i = (long)blockIdx.x * blockDim.x + threadIdx.x; i < total; i += (long)gridDim.x * blockDim.x){
    int mj = (int)(i & 127); long r = i >> 7;
    int kg = (int)(r % KG); long r2 = r / KG;
    int qr = (int)(r2 & 15); int b = (int)(r2 >> 4);
    int mm = mj >> 3, j = mj & 7;
    int n = kg * 8 + j, q = qr * 16 + mm;
    float v = (kg < 1250) ? ldin(attn, ((long)(b * Qq + q)) * Nn + n, f) : 0.f;
    aswz[i] = f2b(v);
  }
}
__global__ void swz_s_kernel(const u16* __restrict__ sbm, u16* __restrict__ sswz)
{
  const long total = (long)Bx * KG * 128;
  for (long i = (long)blockIdx.x * blockDim.x + threadIdx.x; i < total; i += (long)gridDim.x * blockDim.x){
    int d = (int)(i & 127); long r = i >> 7;
    int kg = (int)(r % KG); int b = (int)(r / KG);
    union { u16 h[8]; uint4 v[2]; } t;
    if (kg < 1250){
      #pragma unroll
      for (int j = 0; j < 8; j++)
        t.h[j] = sbm[(((size_t)b * Nn + kg * 8 + j) << 7) + d];
    } else {
      #pragma unroll
      for (int j = 0; j < 8; j++) t.h[j] = 0;
    }
    *(uint4*)(sswz + i * 8) = t.v[0];
    *(uint4*)(sswz + i * 8 + 8) = t.v[1];
  }
}
__global__ __launch_bounds__(256) void extract2_kernel(
  const u16* __restrict__ aswz, const u16* __restrict__ sswz, float* __restrict__ part)
{
  int blk = blockIdx.x;
  int kc = blk & 15, qt = (blk >> 4) & 3, b = blk >> 6;
  int tid = threadIdx.x, w = tid >> 6, lane = tid & 63, m = lane & 15, quad = lane >> 4;
  int qr = qt * 4 + w, q0 = qr * 16;
  int kg0 = kc * 80;
  int nsteps = (kc == 15) ? 13 : 20;
  const u16* abase = aswz + ((size_t)(b * 16 + qr)) * KG * 128;
  const u16* sbase = sswz + ((size_t)b) * KG * 1024;
  f32x4 acc[8];
  const f32x4 z4 = {0.f, 0.f, 0.f, 0.f};
  #pragma unroll
  for (int ct = 0; ct < 8; ct++) acc[ct] = z4;
  #pragma unroll 1
  for (int t = 0; t < nsteps; t++){
    int kg = kg0 + t * 4 + quad;
    bf16x8 a = *(const bf16x8*)(abase + (size_t)kg * 128 + m * 8);
    #pragma unroll
    for (int ct = 0; ct < 8; ct++){
      bf16x8 bv = *(const bf16x8*)(sbase + ((size_t)kg * 128 + ct * 16 + m) * 8);
      acc[ct] = __builtin_amdgcn_mfma_f32_16x16x32_bf16(a, bv, acc[ct], 0, 0, 0);
    }
  }
  #pragma unroll
  for (int ct = 0; ct < 8; ct++){
    #pragma unroll
    for (int i = 0; i < 4; i++)
      part[(((size_t)(kc * 4 + b)) * Qq + q0 + quad * 4 + i) * 128 + ct * 16 + m] = acc[ct][i];
  }
}

// ---------------- finalize: out = [poses | sum(16 partials)] ----------------
__global__ void final_kernel(const void* __restrict__ poses, const int* __restrict__ flag,
                             const float* __restrict__ part, void* __restrict__ out)
{
  int f = *flag;
  const long total = (long)Bx * Qq * (Pp + Dd);
  for (long idx = (long)blockIdx.x * blockDim.x + threadIdx.x; idx < total; idx += (long)gridDim.x * blockDim.x){
    int j = (int)(idx % (Pp + Dd));
    long bq = idx / (Pp + Dd);
    float v;
    if (j < Pp){
      v = ldin(poses, bq * Pp + j, f);
    } else {
      int dd = j - Pp;
      int b = (int)(bq >> 8), q = (int)(bq & 255);
      v = 0.f;
      #pragma unroll
      for (int kc = 0; kc < 16; kc++)
        v += part[(((size_t)(kc * 4 + b) * Qq + q) << 7) + dd];
    }
    if (f) ((u16*)out)[idx] = f2b(v);
    else ((float*)out)[idx] = v;
  }
}

extern "C" void kernel_launch(void* const* d_in, const int* in_sizes, int n_in,
                              void* d_out, int out_size, void* d_ws, size_t ws_size,
                              hipStream_t stream)
{
  const void* in_states = d_in[0];
  const void* in_poses  = d_in[1];
  const void* in_attn   = d_in[2];
  const int*  in_src    = (const int*)d_in[3];
  const int*  in_snk    = (const int*)d_in[4];
  const void* in_w1e = d_in[5];  const void* in_b1e = d_in[6];
  const void* in_w2e = d_in[7];  const void* in_b2e = d_in[8];
  const void* in_w1n = d_in[9];  const void* in_b1n = d_in[10];
  const void* in_w2n = d_in[11]; const void* in_b2n = d_in[12];

  char* ws = (char*)d_ws;
  size_t off = 0;
  auto alloc = [&](size_t bytes){ size_t o = off; off = (off + bytes + 255) & ~(size_t)255; return o; };
  size_t o_sf   = alloc((size_t)Bx * Nn * Dd * 4);
  size_t o_sb   = alloc((size_t)Bx * Nn * Dd * 2);
  size_t o_rowp = alloc((size_t)(Nn + 1) * 4);
  size_t o_rcnt = alloc((size_t)Nn * 4);
  size_t o_eidx = alloc((size_t)Ee * 4);
  size_t o_w1e  = alloc(32768 * 2);
  size_t o_w2e  = alloc(8192 * 2);
  size_t o_w1n  = alloc(24576 * 2);
  size_t o_w2n  = alloc(16384 * 2);
  size_t o_b1e  = alloc(128 * 4);
  size_t o_b2e  = alloc(64 * 4);
  size_t o_b1n  = alloc(128 * 4);
  size_t o_b2n  = alloc(128 * 4);
  size_t o_flag = alloc(4);

  size_t msgPerB = (size_t)Ee * Mm * 2;            // 20.5 MB
  size_t aswzB = (size_t)Bx * 16 * KG * 128 * 2;   // 20.5 MB
  size_t sswzB = (size_t)Bx * KG * 128 * 8 * 2;    // 10.3 MB
  size_t partB = (size_t)16 * Bx * Qq * Dd * 4;    // 8.4 MB
  size_t swzTot = ((aswzB + 255) & ~(size_t)255) + ((sswzB + 255) & ~(size_t)255) + partB;
  size_t region = 4 * msgPerB;
  if (region < swzTot) region = swzTot;
  size_t o_msg = alloc(region);

  float* sf    = (float*)(ws + o_sf);
  u16*   sbm   = (u16*)(ws + o_sb);
  int*   rowp  = (int*)(ws + o_rowp);
  int*   rcnt  = (int*)(ws + o_rcnt);
  int*   eidx  = (int*)(ws + o_eidx);
  u16*   w1e_s = (u16*)(ws + o_w1e);
  u16*   w2e_s = (u16*)(ws + o_w2e);
  u16*   w1n_s = (u16*)(ws + o_w1n);
  u16*   w2n_s = (u16*)(ws + o_w2n);
  float* b1e_f = (float*)(ws + o_b1e);
  float* b2e_f = (float*)(ws + o_b2e);
  float* b1n_f = (float*)(ws + o_b1n);
  float* b2n_f = (float*)(ws + o_b2n);
  int*   flag  = (int*)(ws + o_flag);
  u16*   msg   = (u16*)(ws + o_msg);
  u16*   aswz  = (u16*)(ws + o_msg);
  u16*   sswz  = (u16*)(ws + o_msg + ((aswzB + 255) & ~(size_t)255));
  float* part  = (float*)(ws + o_msg + ((aswzB + 255) & ~(size_t)255) + ((sswzB + 255) & ~(size_t)255));

  probe_kernel<<<1, 64, 0, stream>>>(in_states, flag);
  prep_kernel<<<322, 256, 0, stream>>>(in_w1e, in_b1e, in_w2e, in_b2e,
                                       in_w1n, in_b1n, in_w2n, in_b2n, flag,
                                       w1e_s, w2e_s, w1n_s, w2n_s,
                                       b1e_f, b2e_f, b1n_f, b2n_f);
  init_states_kernel<<<1024, 256, 0, stream>>>(in_states, flag, sf, sbm);

  hipMemsetAsync(rcnt, 0, (size_t)Nn * 4, stream);
  count_kernel<<<(Ee + 255) / 256, 256, 0, stream>>>(in_snk, rcnt);
  scan_kernel<<<1, 1024, 0, stream>>>(rcnt, rowp);
  hipMemsetAsync(rcnt, 0, (size_t)Nn * 4, stream);
  fill_kernel<<<(Ee + 255) / 256, 256, 0, stream>>>(in_snk, rowp, rcnt, eidx);

  for (int step = 0; step < 3; step++){
    edge_kernel<<<5000, 256, 0, stream>>>(sbm, in_src, in_snk, w1e_s, w2e_s,
                                          b1e_f, b2e_f, msg);
    node_kernel<<<632, 256, 0, stream>>>(sf, sbm, msg, rowp, eidx,
                                         w1n_s, w2n_s, b1n_f, b2n_f);
  }
  swz_attn_kernel<<<8192, 256, 0, stream>>>(in_attn, flag, aswz);
  swz_s_kernel<<<2504, 256, 0, stream>>>(sbm, sswz);
  extract2_kernel<<<256, 256, 0, stream>>>(aswz, sswz, part);
  final_kernel<<<540, 256, 0, stream>>>(in_poses, flag, part, d_out);
}

// Round 7
// 572.245 us; speedup vs baseline: 1.7790x; 1.7547x over previous
//
#include <hip/hip_runtime.h>

// Problem constants (from reference)
#define Bx 4
#define Nn 10000
#define Ee 160000
#define Qq 256
#define Dd 128
#define Mm 64
#define Uu 126
#define Hh 128
#define Pp 7

// N padded to groups of 8 (1250 groups) + 2 pad groups for ragged K-tail
#define KG 1252

typedef unsigned short u16;
typedef __bf16 bf16x8 __attribute__((ext_vector_type(8)));
typedef float f32x4 __attribute__((ext_vector_type(4)));

__device__ __forceinline__ float b2f(u16 h){
  unsigned u = ((unsigned)h) << 16; float f; __builtin_memcpy(&f, &u, 4); return f;
}
__device__ __forceinline__ u16 f2b(float f){
  unsigned u; __builtin_memcpy(&u, &f, 4);
  u = (u + 0x7FFFu + ((u >> 16) & 1u)) >> 16;   // RNE
  return (u16)u;
}
__device__ __forceinline__ float ldin(const void* p, long i, int flag){
  return flag ? b2f(((const u16*)p)[i]) : ((const float*)p)[i];
}
__device__ __forceinline__ void acc2bf(float& a0, float& a1, unsigned v){
  a0 += b2f((u16)(v & 0xffffu));
  a1 += b2f((u16)(v >> 16));
}

// ---------------- dtype probe ----------------
__global__ void probe_kernel(const void* in0, int* flag){
  if (threadIdx.x == 0 && blockIdx.x == 0){
    const u16* p = (const u16*)in0;
    int cnt = 0;
    for (int i = 0; i < 256; i++){
      float a = fabsf(b2f(p[i]));
      if (a > 0.0009765625f && a < 32.0f) cnt++;
    }
    *flag = (cnt >= 240) ? 1 : 0;
  }
}

// ---------------- weight prep: convert + swizzle to MFMA B-frag layout ----------------
__global__ void prep_kernel(const void* w1e, const void* b1e, const void* w2e, const void* b2e,
                            const void* w1n, const void* b1n, const void* w2n, const void* b2n,
                            const int* __restrict__ flag,
                            u16* w1e_s, u16* w2e_s, u16* w1n_s, u16* w2n_s,
                            float* b1e_f, float* b2e_f, float* b1n_f, float* b2n_f)
{
  int f = *flag;
  for (int idx = blockIdx.x * blockDim.x + threadIdx.x; idx < 82368; idx += gridDim.x * blockDim.x){
    if (idx < 32768){                                   // w1e (256,128)
      int k = idx >> 7, h = idx & 127;
      w1e_s[(k >> 3) * 1024 + h * 8 + (k & 7)] = f2b(ldin(w1e, idx, f));
    } else if (idx < 40960){                            // w2e (128,64)
      int i2 = idx - 32768; int k = i2 >> 6, m2 = i2 & 63;
      w2e_s[(k >> 3) * 512 + m2 * 8 + (k & 7)] = f2b(ldin(w2e, i2, f));
    } else if (idx < 65536){                            // w1n (192,128)
      int i2 = idx - 40960; int k = i2 >> 7, h = i2 & 127;
      w1n_s[(k >> 3) * 1024 + h * 8 + (k & 7)] = f2b(ldin(w1n, i2, f));
    } else if (idx < 81920){                            // w2n (128,126) padded to 128 cols
      int i2 = idx - 65536; int k = i2 >> 7, u = i2 & 127;
      float v = (u < 126) ? ldin(w2n, (long)k * 126 + u, f) : 0.f;
      w2n_s[(k >> 3) * 1024 + u * 8 + (k & 7)] = f2b(v);
    } else if (idx < 82048){ b1e_f[idx - 81920] = ldin(b1e, idx - 81920, f); }
    else if (idx < 82112){ b2e_f[idx - 82048] = ldin(b2e, idx - 82048, f); }
    else if (idx < 82240){ b1n_f[idx - 82112] = ldin(b1n, idx - 82112, f); }
    else { int j = idx - 82240; b2n_f[j] = (j < 126) ? ldin(b2n, j, f) : 0.f; }
  }
}

// ---------------- init: f32 master states + bf16 mirror ----------------
__global__ void init_states_kernel(const void* in0, const int* __restrict__ flag,
                                   float* __restrict__ sf, u16* __restrict__ sbm)
{
  int f = *flag;
  const long total = (long)Bx * Nn * Dd;
  for (long i = (long)blockIdx.x * blockDim.x + threadIdx.x; i < total; i += (long)gridDim.x * blockDim.x){
    float v = ldin(in0, i, f);
    sf[i] = v; sbm[i] = f2b(v);
  }
}

// ---------------- CSR build ----------------
__global__ void count_kernel(const int* __restrict__ snk, int* __restrict__ cnt){
  int i = blockIdx.x * blockDim.x + threadIdx.x;
  if (i < Ee) atomicAdd(&cnt[snk[i]], 1);
}
__global__ void scan_kernel(const int* __restrict__ cnt, int* __restrict__ rowp){
  __shared__ int tot[1024];
  int t = threadIdx.x;
  int base = t * 10;
  int local[10]; int s = 0;
  #pragma unroll
  for (int i = 0; i < 10; i++){
    int v = (base + i < Nn) ? cnt[base + i] : 0;
    local[i] = s; s += v;
  }
  tot[t] = s;
  __syncthreads();
  for (int o = 1; o < 1024; o <<= 1){
    int v = (t >= o) ? tot[t - o] : 0;
    __syncthreads();
    tot[t] += v;
    __syncthreads();
  }
  int prefix = (t == 0) ? 0 : tot[t - 1];
  #pragma unroll
  for (int i = 0; i < 10; i++)
    if (base + i < Nn) rowp[base + i] = prefix + local[i];
  if (t == 1023) rowp[Nn] = tot[1023];
}
__global__ void fill_kernel(const int* __restrict__ snk, const int* __restrict__ rowp,
                            int* __restrict__ cnt, int* __restrict__ eidx){
  int i = blockIdx.x * blockDim.x + threadIdx.x;
  if (i < Ee){
    int s = snk[i];
    int p = rowp[s] + atomicAdd(&cnt[s], 1);
    eidx[p] = i;
  }
}

// ---------------- edge MLP v7 ----------------
// Identical to v5 EXCEPT: the s (subtile) and ph (hidden-phase) loops are FULLY
// unrolled. v2/v4/v5/v6 lesson: `#pragma unroll 1` over a runtime index into
// acc1[2][8] forces the accumulator array into SCRATCH (no dynamic register
// indexing) -> every MFMA does a private-memory RMW -> ~1GB HBM writes.
// Full unroll makes all accumulator indices compile-time -> registers.
__global__ __launch_bounds__(512) void edge_kernel(
  const u16* __restrict__ sbm, const int* __restrict__ src, const int* __restrict__ snk,
  const u16* __restrict__ w1s, const u16* __restrict__ w2s,
  const float* __restrict__ b1f, const float* __restrict__ b2f2,
  u16* __restrict__ msg)
{
  __shared__ __align__(16) u16 w1h[16384];     // 32KB: one K-half of w1e, swizzled
  __shared__ __align__(16) u16 Yt[128 * 72];   // 18KB: hidden phase / store transpose
  __shared__ float b1l[128];
  __shared__ float b2l[64];
  int tid = threadIdx.x;
  if (tid < 128) b1l[tid] = b1f[tid];
  else if (tid < 192) b2l[tid - 128] = b2f2[tid - 128];

  // blockIdx % 8 -> XCD; batch pinned to an XCD pair. 2504 blocks; tile<625 guard.
  int b = (blockIdx.x & 7) >> 1;
  int tile = ((blockIdx.x >> 3) << 1) + (blockIdx.x & 1);
  if (tile >= 625) return;                     // uniform per block; before any barrier
  int e0 = tile * 256;
  int w = tid >> 6, lane = tid & 63, m = lane & 15, quad = lane >> 4;
  int ebase = e0 + w * 32;
  int eA = ebase + m, eB = ebase + 16 + m;
  int src0 = src[eA], src1 = src[eB];
  int snk0 = snk[eA], snk1 = snk[eB];
  const u16* sbase = sbm + (((size_t)b * Nn) << 7);

  // prefetch src-rows (gather latency hides under half-0 staging)
  bf16x8 aS0[4], aS1[4];
  {
    const u16* r0 = sbase + ((size_t)src0 << 7);
    const u16* r1 = sbase + ((size_t)src1 << 7);
    #pragma unroll
    for (int lk = 0; lk < 4; lk++){
      aS0[lk] = *(const bf16x8*)(r0 + lk * 32 + quad * 8);
      aS1[lk] = *(const bf16x8*)(r1 + lk * 32 + quad * 8);
    }
  }

  f32x4 acc1[2][8];
  const f32x4 z4 = {0.f, 0.f, 0.f, 0.f};
  #pragma unroll
  for (int s = 0; s < 2; s++)
    #pragma unroll
    for (int ct = 0; ct < 8; ct++) acc1[s][ct] = z4;

  // ---- layer 1, K-half 0 (src rows) ----
  {
    const uint4* g = (const uint4*)(w1s);
    uint4* l = (uint4*)w1h;
    #pragma unroll
    for (int i = 0; i < 4; i++) l[tid + i * 512] = g[tid + i * 512];
  }
  __syncthreads();
  #pragma unroll
  for (int lk = 0; lk < 4; lk++){
    #pragma unroll
    for (int ct = 0; ct < 8; ct++){
      bf16x8 bv = *(const bf16x8*)(w1h + (((lk * 4 + quad) << 7) + ct * 16 + m) * 8);
      acc1[0][ct] = __builtin_amdgcn_mfma_f32_16x16x32_bf16(aS0[lk], bv, acc1[0][ct], 0, 0, 0);
      acc1[1][ct] = __builtin_amdgcn_mfma_f32_16x16x32_bf16(aS1[lk], bv, acc1[1][ct], 0, 0, 0);
    }
  }
  // prefetch snk-rows (overlaps half-1 staging wait)
  bf16x8 aK0[4], aK1[4];
  {
    const u16* r0 = sbase + ((size_t)snk0 << 7);
    const u16* r1 = sbase + ((size_t)snk1 << 7);
    #pragma unroll
    for (int lk = 0; lk < 4; lk++){
      aK0[lk] = *(const bf16x8*)(r0 + lk * 32 + quad * 8);
      aK1[lk] = *(const bf16x8*)(r1 + lk * 32 + quad * 8);
    }
  }
  __syncthreads();
  // ---- layer 1, K-half 1 (snk rows) ----
  {
    const uint4* g = (const uint4*)(w1s + 16384);
    uint4* l = (uint4*)w1h;
    #pragma unroll
    for (int i = 0; i < 4; i++) l[tid + i * 512] = g[tid + i * 512];
  }
  __syncthreads();
  #pragma unroll
  for (int lk = 0; lk < 4; lk++){
    #pragma unroll
    for (int ct = 0; ct < 8; ct++){
      bf16x8 bv = *(const bf16x8*)(w1h + (((lk * 4 + quad) << 7) + ct * 16 + m) * 8);
      acc1[0][ct] = __builtin_amdgcn_mfma_f32_16x16x32_bf16(aK0[lk], bv, acc1[0][ct], 0, 0, 0);
      acc1[1][ct] = __builtin_amdgcn_mfma_f32_16x16x32_bf16(aK1[lk], bv, acc1[1][ct], 0, 0, 0);
    }
  }

  // ---- layer 2 per subtile: two 64-col phases; Yt rows wave-private ----
  #pragma unroll
  for (int s = 0; s < 2; s++){
    f32x4 acc2[4];
    #pragma unroll
    for (int ct = 0; ct < 4; ct++) acc2[ct] = z4;
    #pragma unroll
    for (int ph = 0; ph < 2; ph++){
      #pragma unroll
      for (int c = 0; c < 4; c++){
        int ct = ph * 4 + c;
        #pragma unroll
        for (int i = 0; i < 4; i++){
          float v = acc1[s][ct][i] + b1l[ct * 16 + m];
          v = v > 0.f ? v : 0.f;
          Yt[(w * 16 + quad * 4 + i) * 72 + c * 16 + m] = f2b(v);
        }
      }
      #pragma unroll
      for (int lk = 0; lk < 2; lk++){
        int ko = ph * 2 + lk;
        bf16x8 a2 = *(const bf16x8*)(Yt + (w * 16 + m) * 72 + lk * 32 + quad * 8);
        #pragma unroll
        for (int ct = 0; ct < 4; ct++){
          bf16x8 bv = *(const bf16x8*)(w2s + (((ko * 4 + quad) << 6) + ct * 16 + m) * 8);
          acc2[ct] = __builtin_amdgcn_mfma_f32_16x16x32_bf16(a2, bv, acc2[ct], 0, 0, 0);
        }
      }
    }
    // transpose C through Yt (same-wave DS ordering), store 16 SEQUENTIAL rows (2KB contiguous)
    #pragma unroll
    for (int ct = 0; ct < 4; ct++){
      #pragma unroll
      for (int i = 0; i < 4; i++){
        float v = acc2[ct][i] + b2l[ct * 16 + m];
        Yt[(w * 16 + quad * 4 + i) * 72 + ct * 16 + m] = f2b(v);
      }
    }
    int row_l = lane >> 2, seg = lane & 3;
    const uint4* tp = (const uint4*)(Yt + (w * 16 + row_l) * 72 + seg * 16);
    uint4 x0 = tp[0], x1 = tp[1];
    uint4* gp = (uint4*)(msg + (((size_t)b * Ee + ebase + s * 16 + row_l) << 6) + seg * 16);
    gp[0] = x0; gp[1] = x1;
  }
}

// ---------------- node MLP: CSR gather via eidx indirection ----------------
__global__ __launch_bounds__(256) void node_kernel(
  float* __restrict__ sf, u16* __restrict__ sbm,
  const u16* __restrict__ msg, const int* __restrict__ rowp, const int* __restrict__ eidx,
  const u16* __restrict__ w1s, const u16* __restrict__ w2s,
  const float* __restrict__ b1f, const float* __restrict__ b2f2)
{
  __shared__ __align__(16) u16 ninp[64 * 200];
  __shared__ __align__(16) u16 Yt[64 * 136];
  __shared__ float b1l[128];
  __shared__ float b2l[128];
  int b = (blockIdx.x & 7) >> 1;
  int nt = ((blockIdx.x >> 3) << 1) + (blockIdx.x & 1);
  if (nt >= 157) return;                       // uniform per block
  int n0 = nt * 64;
  int tid = threadIdx.x;
  if (tid < 128) b1l[tid] = b1f[tid];
  else b2l[tid - 128] = b2f2[tid - 128];

  {
    int nl = tid >> 2, part = tid & 3;
    int n = n0 + nl;
    float acc[16];
    #pragma unroll
    for (int i = 0; i < 16; i++) acc[i] = 0.f;
    if (n < Nn){
      int r0 = rowp[n], r1 = rowp[n + 1];
      const u16* mb = msg + (((size_t)b * Ee) << 6) + part * 16;
      for (int j = r0; j < r1; j++){
        int e = eidx[j];
        const uint4* mp = (const uint4*)(mb + ((size_t)e << 6));
        uint4 p0 = mp[0], p1 = mp[1];
        acc2bf(acc[0], acc[1], p0.x);  acc2bf(acc[2], acc[3], p0.y);
        acc2bf(acc[4], acc[5], p0.z);  acc2bf(acc[6], acc[7], p0.w);
        acc2bf(acc[8], acc[9], p1.x);  acc2bf(acc[10], acc[11], p1.y);
        acc2bf(acc[12], acc[13], p1.z); acc2bf(acc[14], acc[15], p1.w);
      }
    }
    union { u16 h[16]; uint4 v[2]; } tb;
    #pragma unroll
    for (int i = 0; i < 16; i++) tb.h[i] = f2b(acc[i]);
    *(uint4*)(ninp + nl * 200 + part * 16) = tb.v[0];
    *(uint4*)(ninp + nl * 200 + part * 16 + 8) = tb.v[1];
    uint4* dp = (uint4*)(ninp + nl * 200 + 64 + part * 32);
    if (n < Nn){
      const uint4* sp = (const uint4*)(sbm + (((size_t)b * Nn + n) << 7) + part * 32);
      #pragma unroll
      for (int i = 0; i < 4; i++) dp[i] = sp[i];
    } else {
      uint4 zz = {0, 0, 0, 0};
      #pragma unroll
      for (int i = 0; i < 4; i++) dp[i] = zz;
    }
  }
  __syncthreads();

  int w = tid >> 6, lane = tid & 63, m = lane & 15, quad = lane >> 4;
  const f32x4 z4 = {0.f, 0.f, 0.f, 0.f};
  f32x4 acc1[8];
  #pragma unroll
  for (int ct = 0; ct < 8; ct++) acc1[ct] = z4;
  #pragma unroll 1
  for (int ks = 0; ks < 6; ks++){
    bf16x8 a = *(const bf16x8*)(ninp + (w * 16 + m) * 200 + ks * 32 + quad * 8);
    #pragma unroll
    for (int ct = 0; ct < 8; ct++){
      bf16x8 bv = *(const bf16x8*)(w1s + (((ks * 4 + quad) << 7) + ct * 16 + m) * 8);
      acc1[ct] = __builtin_amdgcn_mfma_f32_16x16x32_bf16(a, bv, acc1[ct], 0, 0, 0);
    }
  }
  #pragma unroll
  for (int ct = 0; ct < 8; ct++){
    #pragma unroll
    for (int i = 0; i < 4; i++){
      float v = acc1[ct][i] + b1l[ct * 16 + m];
      v = v > 0.f ? v : 0.f;
      Yt[(w * 16 + quad * 4 + i) * 136 + ct * 16 + m] = f2b(v);
    }
  }
  f32x4 acc2[8];
  #pragma unroll
  for (int ct = 0; ct < 8; ct++) acc2[ct] = z4;
  #pragma unroll 1
  for (int ko = 0; ko < 4; ko++){
    bf16x8 a2 = *(const bf16x8*)(Yt + (w * 16 + m) * 136 + ko * 32 + quad * 8);
    #pragma unroll
    for (int ct = 0; ct < 8; ct++){
      bf16x8 bv = *(const bf16x8*)(w2s + (((ko * 4 + quad) << 7) + ct * 16 + m) * 8);
      acc2[ct] = __builtin_amdgcn_mfma_f32_16x16x32_bf16(a2, bv, acc2[ct], 0, 0, 0);
    }
  }
  #pragma unroll
  for (int ct = 0; ct < 8; ct++){
    int u = ct * 16 + m;
    if (u < 126){
      #pragma unroll
      for (int i = 0; i < 4; i++){
        int n = n0 + w * 16 + quad * 4 + i;
        if (n < Nn){
          size_t idx = (((size_t)b * Nn + n) << 7) + 2 + u;
          float v = sf[idx] + acc2[ct][i] + b2l[u];
          sf[idx] = v;
          sbm[idx] = f2b(v);
        }
      }
    }
  }
}

// ---------------- extraction: MFMA GEMM ----------------
__global__ void swz_attn_kernel(const void* __restrict__ attn, const int* __restrict__ flag,
                                u16* __restrict__ aswz)
{
  int f = *flag;
  const long total = (long)Bx * 16 * KG * 128;
  for (long i = (long)blockIdx.x * blockDim.x + threadIdx.x; i < total; i += (long)gridDim.x * blockDim.x){
    int mj = (int)(i & 127); long r = i >> 7;
    int kg = (int)(r % KG); long r2 = r / KG;
    int qr = (int)(r2 & 15); int b = (int)(r2 >> 4);
    int mm = mj >> 3, j = mj & 7;
    int n = kg * 8 + j, q = qr * 16 + mm;
    float v = (kg < 1250) ? ldin(attn, ((long)(b * Qq + q)) * Nn + n, f) : 0.f;
    aswz[i] = f2b(v);
  }
}
__global__ void swz_s_kernel(const u16* __restrict__ sbm, u16* __restrict__ sswz)
{
  const long total = (long)Bx * KG * 128;
  for (long i = (long)blockIdx.x * blockDim.x + threadIdx.x; i < total; i += (long)gridDim.x * blockDim.x){
    int d = (int)(i & 127); long r = i >> 7;
    int kg = (int)(r % KG); int b = (int)(r / KG);
    union { u16 h[8]; uint4 v[2]; } t;
    if (kg < 1250){
      #pragma unroll
      for (int j = 0; j < 8; j++)
        t.h[j] = sbm[(((size_t)b * Nn + kg * 8 + j) << 7) + d];
    } else {
      #pragma unroll
      for (int j = 0; j < 8; j++) t.h[j] = 0;
    }
    *(uint4*)(sswz + i * 8) = t.v[0];
    *(uint4*)(sswz + i * 8 + 8) = t.v[1];
  }
}
__global__ __launch_bounds__(256) void extract2_kernel(
  const u16* __restrict__ aswz, const u16* __restrict__ sswz, float* __restrict__ part)
{
  int blk = blockIdx.x;
  int kc = blk & 15, qt = (blk >> 4) & 3, b = blk >> 6;
  int tid = threadIdx.x, w = tid >> 6, lane = tid & 63, m = lane & 15, quad = lane >> 4;
  int qr = qt * 4 + w, q0 = qr * 16;
  int kg0 = kc * 80;
  int nsteps = (kc == 15) ? 13 : 20;
  const u16* abase = aswz + ((size_t)(b * 16 + qr)) * KG * 128;
  const u16* sbase = sswz + ((size_t)b) * KG * 1024;
  f32x4 acc[8];
  const f32x4 z4 = {0.f, 0.f, 0.f, 0.f};
  #pragma unroll
  for (int ct = 0; ct < 8; ct++) acc[ct] = z4;
  #pragma unroll 1
  for (int t = 0; t < nsteps; t++){
    int kg = kg0 + t * 4 + quad;
    bf16x8 a = *(const bf16x8*)(abase + (size_t)kg * 128 + m * 8);
    #pragma unroll
    for (int ct = 0; ct < 8; ct++){
      bf16x8 bv = *(const bf16x8*)(sbase + ((size_t)kg * 128 + ct * 16 + m) * 8);
      acc[ct] = __builtin_amdgcn_mfma_f32_16x16x32_bf16(a, bv, acc[ct], 0, 0, 0);
    }
  }
  #pragma unroll
  for (int ct = 0; ct < 8; ct++){
    #pragma unroll
    for (int i = 0; i < 4; i++)
      part[(((size_t)(kc * 4 + b)) * Qq + q0 + quad * 4 + i) * 128 + ct * 16 + m] = acc[ct][i];
  }
}

// ---------------- finalize: out = [poses | sum(16 partials)] ----------------
__global__ void final_kernel(const void* __restrict__ poses, const int* __restrict__ flag,
                             const float* __restrict__ part, void* __restrict__ out)
{
  int f = *flag;
  const long total = (long)Bx * Qq * (Pp + Dd);
  for (long idx = (long)blockIdx.x * blockDim.x + threadIdx.x; idx < total; idx += (long)gridDim.x * blockDim.x){
    int j = (int)(idx % (Pp + Dd));
    long bq = idx / (Pp + Dd);
    float v;
    if (j < Pp){
      v = ldin(poses, bq * Pp + j, f);
    } else {
      int dd = j - Pp;
      int b = (int)(bq >> 8), q = (int)(bq & 255);
      v = 0.f;
      #pragma unroll
      for (int kc = 0; kc < 16; kc++)
        v += part[(((size_t)(kc * 4 + b) * Qq + q) << 7) + dd];
    }
    if (f) ((u16*)out)[idx] = f2b(v);
    else ((float*)out)[idx] = v;
  }
}

extern "C" void kernel_launch(void* const* d_in, const int* in_sizes, int n_in,
                              void* d_out, int out_size, void* d_ws, size_t ws_size,
                              hipStream_t stream)
{
  const void* in_states = d_in[0];
  const void* in_poses  = d_in[1];
  const void* in_attn   = d_in[2];
  const int*  in_src    = (const int*)d_in[3];
  const int*  in_snk    = (const int*)d_in[4];
  const void* in_w1e = d_in[5];  const void* in_b1e = d_in[6];
  const void* in_w2e = d_in[7];  const void* in_b2e = d_in[8];
  const void* in_w1n = d_in[9];  const void* in_b1n = d_in[10];
  const void* in_w2n = d_in[11]; const void* in_b2n = d_in[12];

  char* ws = (char*)d_ws;
  size_t off = 0;
  auto alloc = [&](size_t bytes){ size_t o = off; off = (off + bytes + 255) & ~(size_t)255; return o; };
  size_t o_sf   = alloc((size_t)Bx * Nn * Dd * 4);
  size_t o_sb   = alloc((size_t)Bx * Nn * Dd * 2);
  size_t o_rowp = alloc((size_t)(Nn + 1) * 4);
  size_t o_rcnt = alloc((size_t)Nn * 4);
  size_t o_eidx = alloc((size_t)Ee * 4);
  size_t o_w1e  = alloc(32768 * 2);
  size_t o_w2e  = alloc(8192 * 2);
  size_t o_w1n  = alloc(24576 * 2);
  size_t o_w2n  = alloc(16384 * 2);
  size_t o_b1e  = alloc(128 * 4);
  size_t o_b2e  = alloc(64 * 4);
  size_t o_b1n  = alloc(128 * 4);
  size_t o_b2n  = alloc(128 * 4);
  size_t o_flag = alloc(4);

  size_t msgPerB = (size_t)Ee * Mm * 2;            // 20.5 MB
  size_t aswzB = (size_t)Bx * 16 * KG * 128 * 2;   // 20.5 MB
  size_t sswzB = (size_t)Bx * KG * 128 * 8 * 2;    // 10.3 MB
  size_t partB = (size_t)16 * Bx * Qq * Dd * 4;    // 8.4 MB
  size_t swzTot = ((aswzB + 255) & ~(size_t)255) + ((sswzB + 255) & ~(size_t)255) + partB;
  size_t region = 4 * msgPerB;
  if (region < swzTot) region = swzTot;
  size_t o_msg = alloc(region);

  float* sf    = (float*)(ws + o_sf);
  u16*   sbm   = (u16*)(ws + o_sb);
  int*   rowp  = (int*)(ws + o_rowp);
  int*   rcnt  = (int*)(ws + o_rcnt);
  int*   eidx  = (int*)(ws + o_eidx);
  u16*   w1e_s = (u16*)(ws + o_w1e);
  u16*   w2e_s = (u16*)(ws + o_w2e);
  u16*   w1n_s = (u16*)(ws + o_w1n);
  u16*   w2n_s = (u16*)(ws + o_w2n);
  float* b1e_f = (float*)(ws + o_b1e);
  float* b2e_f = (float*)(ws + o_b2e);
  float* b1n_f = (float*)(ws + o_b1n);
  float* b2n_f = (float*)(ws + o_b2n);
  int*   flag  = (int*)(ws + o_flag);
  u16*   msg   = (u16*)(ws + o_msg);
  u16*   aswz  = (u16*)(ws + o_msg);
  u16*   sswz  = (u16*)(ws + o_msg + ((aswzB + 255) & ~(size_t)255));
  float* part  = (float*)(ws + o_msg + ((aswzB + 255) & ~(size_t)255) + ((sswzB + 255) & ~(size_t)255));

  probe_kernel<<<1, 64, 0, stream>>>(in_states, flag);
  prep_kernel<<<322, 256, 0, stream>>>(in_w1e, in_b1e, in_w2e, in_b2e,
                                       in_w1n, in_b1n, in_w2n, in_b2n, flag,
                                       w1e_s, w2e_s, w1n_s, w2n_s,
                                       b1e_f, b2e_f, b1n_f, b2n_f);
  init_states_kernel<<<1024, 256, 0, stream>>>(in_states, flag, sf, sbm);

  hipMemsetAsync(rcnt, 0, (size_t)Nn * 4, stream);
  count_kernel<<<(Ee + 255) / 256, 256, 0, stream>>>(in_snk, rcnt);
  scan_kernel<<<1, 1024, 0, stream>>>(rcnt, rowp);
  hipMemsetAsync(rcnt, 0, (size_t)Nn * 4, stream);
  fill_kernel<<<(Ee + 255) / 256, 256, 0, stream>>>(in_snk, rowp, rcnt, eidx);

  for (int step = 0; step < 3; step++){
    edge_kernel<<<2504, 512, 0, stream>>>(sbm, in_src, in_snk, w1e_s, w2e_s,
                                          b1e_f, b2e_f, msg);
    node_kernel<<<632, 256, 0, stream>>>(sf, sbm, msg, rowp, eidx,
                                         w1n_s, w2n_s, b1n_f, b2n_f);
  }
  swz_attn_kernel<<<8192, 256, 0, stream>>>(in_attn, flag, aswz);
  swz_s_kernel<<<2504, 256, 0, stream>>>(sbm, sswz);
  extract2_kernel<<<256, 256, 0, stream>>>(aswz, sswz, part);
  final_kernel<<<540, 256, 0, stream>>>(in_poses, flag, part, d_out);
}

// Round 8
// 528.546 us; speedup vs baseline: 1.9261x; 1.0827x over previous
//
#include <hip/hip_runtime.h>

// Problem constants (from reference)
#define Bx 4
#define Nn 10000
#define Ee 160000
#define Qq 256
#define Dd 128
#define Mm 64
#define Uu 126
#define Hh 128
#define Pp 7

// N padded to groups of 8 (1250 groups) + 2 pad groups for ragged K-tail
#define KG 1252

typedef unsigned short u16;
typedef __bf16 bf16x8 __attribute__((ext_vector_type(8)));
typedef float f32x4 __attribute__((ext_vector_type(4)));

__device__ __forceinline__ float b2f(u16 h){
  unsigned u = ((unsigned)h) << 16; float f; __builtin_memcpy(&f, &u, 4); return f;
}
__device__ __forceinline__ u16 f2b(float f){
  unsigned u; __builtin_memcpy(&u, &f, 4);
  u = (u + 0x7FFFu + ((u >> 16) & 1u)) >> 16;   // RNE
  return (u16)u;
}
__device__ __forceinline__ float ldin(const void* p, long i, int flag){
  return flag ? b2f(((const u16*)p)[i]) : ((const float*)p)[i];
}
__device__ __forceinline__ void acc2bf(float& a0, float& a1, unsigned v){
  a0 += b2f((u16)(v & 0xffffu));
  a1 += b2f((u16)(v >> 16));
}

// ---------------- dtype probe ----------------
__global__ void probe_kernel(const void* in0, int* flag){
  if (threadIdx.x == 0 && blockIdx.x == 0){
    const u16* p = (const u16*)in0;
    int cnt = 0;
    for (int i = 0; i < 256; i++){
      float a = fabsf(b2f(p[i]));
      if (a > 0.0009765625f && a < 32.0f) cnt++;
    }
    *flag = (cnt >= 240) ? 1 : 0;
  }
}

// ---------------- weight prep: convert + swizzle to MFMA B-frag layout ----------------
__global__ void prep_kernel(const void* w1e, const void* b1e, const void* w2e, const void* b2e,
                            const void* w1n, const void* b1n, const void* w2n, const void* b2n,
                            const int* __restrict__ flag,
                            u16* w1e_s, u16* w2e_s, u16* w1n_s, u16* w2n_s,
                            float* b1e_f, float* b2e_f, float* b1n_f, float* b2n_f)
{
  int f = *flag;
  for (int idx = blockIdx.x * blockDim.x + threadIdx.x; idx < 82368; idx += gridDim.x * blockDim.x){
    if (idx < 32768){                                   // w1e (256,128)
      int k = idx >> 7, h = idx & 127;
      w1e_s[(k >> 3) * 1024 + h * 8 + (k & 7)] = f2b(ldin(w1e, idx, f));
    } else if (idx < 40960){                            // w2e (128,64)
      int i2 = idx - 32768; int k = i2 >> 6, m2 = i2 & 63;
      w2e_s[(k >> 3) * 512 + m2 * 8 + (k & 7)] = f2b(ldin(w2e, i2, f));
    } else if (idx < 65536){                            // w1n (192,128)
      int i2 = idx - 40960; int k = i2 >> 7, h = i2 & 127;
      w1n_s[(k >> 3) * 1024 + h * 8 + (k & 7)] = f2b(ldin(w1n, i2, f));
    } else if (idx < 81920){                            // w2n (128,126) padded to 128 cols
      int i2 = idx - 65536; int k = i2 >> 7, u = i2 & 127;
      float v = (u < 126) ? ldin(w2n, (long)k * 126 + u, f) : 0.f;
      w2n_s[(k >> 3) * 1024 + u * 8 + (k & 7)] = f2b(v);
    } else if (idx < 82048){ b1e_f[idx - 81920] = ldin(b1e, idx - 81920, f); }
    else if (idx < 82112){ b2e_f[idx - 82048] = ldin(b2e, idx - 82048, f); }
    else if (idx < 82240){ b1n_f[idx - 82112] = ldin(b1n, idx - 82112, f); }
    else { int j = idx - 82240; b2n_f[j] = (j < 126) ? ldin(b2n, j, f) : 0.f; }
  }
}

// ---------------- init: f32 master states + bf16 mirror ----------------
__global__ void init_states_kernel(const void* in0, const int* __restrict__ flag,
                                   float* __restrict__ sf, u16* __restrict__ sbm)
{
  int f = *flag;
  const long total = (long)Bx * Nn * Dd;
  for (long i = (long)blockIdx.x * blockDim.x + threadIdx.x; i < total; i += (long)gridDim.x * blockDim.x){
    float v = ldin(in0, i, f);
    sf[i] = v; sbm[i] = f2b(v);
  }
}

// ---------------- CSR build ----------------
__global__ void count_kernel(const int* __restrict__ snk, int* __restrict__ cnt){
  int i = blockIdx.x * blockDim.x + threadIdx.x;
  if (i < Ee) atomicAdd(&cnt[snk[i]], 1);
}
__global__ void scan_kernel(const int* __restrict__ cnt, int* __restrict__ rowp){
  __shared__ int tot[1024];
  int t = threadIdx.x;
  int base = t * 10;
  int local[10]; int s = 0;
  #pragma unroll
  for (int i = 0; i < 10; i++){
    int v = (base + i < Nn) ? cnt[base + i] : 0;
    local[i] = s; s += v;
  }
  tot[t] = s;
  __syncthreads();
  for (int o = 1; o < 1024; o <<= 1){
    int v = (t >= o) ? tot[t - o] : 0;
    __syncthreads();
    tot[t] += v;
    __syncthreads();
  }
  int prefix = (t == 0) ? 0 : tot[t - 1];
  #pragma unroll
  for (int i = 0; i < 10; i++)
    if (base + i < Nn) rowp[base + i] = prefix + local[i];
  if (t == 1023) rowp[Nn] = tot[1023];
}
// CSR-ordered endpoint lists: slot p holds (src, snk) of the edge at CSR position p.
// Edge kernel processes slots in order -> sequential msg stores + near-sorted snk gathers.
__global__ void fill_kernel(const int* __restrict__ src, const int* __restrict__ snk,
                            const int* __restrict__ rowp, int* __restrict__ cnt,
                            int* __restrict__ psrc, int* __restrict__ psnk){
  int i = blockIdx.x * blockDim.x + threadIdx.x;
  if (i < Ee){
    int s = snk[i];
    int p = rowp[s] + atomicAdd(&cnt[s], 1);
    psrc[p] = src[i];
    psnk[p] = s;
  }
}

// ---------------- edge MLP v8: CSR-ordered ----------------
// Same compute structure as v7 (2 subtiles/wave, full unroll — NEVER runtime-index
// the accumulator array: `#pragma unroll 1` over acc1[s] sent it to scratch ->
// 1GB HBM writes in v2/v4/v5/v6). Edges processed in CSR order via psrc/psnk:
// index loads coalesced, snk-row gathers near-sequential (L1/L2 reuse),
// msg stores sequential-contiguous at the CSR slot.
__global__ __launch_bounds__(512) void edge_kernel(
  const u16* __restrict__ sbm, const int* __restrict__ psrc, const int* __restrict__ psnk,
  const u16* __restrict__ w1s, const u16* __restrict__ w2s,
  const float* __restrict__ b1f, const float* __restrict__ b2f2,
  u16* __restrict__ msg)
{
  __shared__ __align__(16) u16 w1h[16384];     // 32KB: one K-half of w1e, swizzled
  __shared__ __align__(16) u16 Yt[128 * 72];   // 18KB: hidden phase / store transpose
  __shared__ float b1l[128];
  __shared__ float b2l[64];
  int tid = threadIdx.x;
  if (tid < 128) b1l[tid] = b1f[tid];
  else if (tid < 192) b2l[tid - 128] = b2f2[tid - 128];

  // blockIdx % 8 -> XCD; batch pinned to an XCD pair. 2504 blocks; tile<625 guard.
  int b = (blockIdx.x & 7) >> 1;
  int tile = ((blockIdx.x >> 3) << 1) + (blockIdx.x & 1);
  if (tile >= 625) return;                     // uniform per block; before any barrier
  int e0 = tile * 256;
  int w = tid >> 6, lane = tid & 63, m = lane & 15, quad = lane >> 4;
  int ebase = e0 + w * 32;
  int eA = ebase + m, eB = ebase + 16 + m;
  int src0 = psrc[eA], src1 = psrc[eB];
  int snk0 = psnk[eA], snk1 = psnk[eB];
  const u16* sbase = sbm + (((size_t)b * Nn) << 7);

  // prefetch src-rows (gather latency hides under half-0 staging)
  bf16x8 aS0[4], aS1[4];
  {
    const u16* r0 = sbase + ((size_t)src0 << 7);
    const u16* r1 = sbase + ((size_t)src1 << 7);
    #pragma unroll
    for (int lk = 0; lk < 4; lk++){
      aS0[lk] = *(const bf16x8*)(r0 + lk * 32 + quad * 8);
      aS1[lk] = *(const bf16x8*)(r1 + lk * 32 + quad * 8);
    }
  }

  f32x4 acc1[2][8];
  const f32x4 z4 = {0.f, 0.f, 0.f, 0.f};
  #pragma unroll
  for (int s = 0; s < 2; s++)
    #pragma unroll
    for (int ct = 0; ct < 8; ct++) acc1[s][ct] = z4;

  // ---- layer 1, K-half 0 (src rows) ----
  {
    const uint4* g = (const uint4*)(w1s);
    uint4* l = (uint4*)w1h;
    #pragma unroll
    for (int i = 0; i < 4; i++) l[tid + i * 512] = g[tid + i * 512];
  }
  __syncthreads();
  #pragma unroll
  for (int lk = 0; lk < 4; lk++){
    #pragma unroll
    for (int ct = 0; ct < 8; ct++){
      bf16x8 bv = *(const bf16x8*)(w1h + (((lk * 4 + quad) << 7) + ct * 16 + m) * 8);
      acc1[0][ct] = __builtin_amdgcn_mfma_f32_16x16x32_bf16(aS0[lk], bv, acc1[0][ct], 0, 0, 0);
      acc1[1][ct] = __builtin_amdgcn_mfma_f32_16x16x32_bf16(aS1[lk], bv, acc1[1][ct], 0, 0, 0);
    }
  }
  // prefetch snk-rows (near-sequential in CSR order -> L1/L2 hits; overlaps half-1 staging)
  bf16x8 aK0[4], aK1[4];
  {
    const u16* r0 = sbase + ((size_t)snk0 << 7);
    const u16* r1 = sbase + ((size_t)snk1 << 7);
    #pragma unroll
    for (int lk = 0; lk < 4; lk++){
      aK0[lk] = *(const bf16x8*)(r0 + lk * 32 + quad * 8);
      aK1[lk] = *(const bf16x8*)(r1 + lk * 32 + quad * 8);
    }
  }
  __syncthreads();
  // ---- layer 1, K-half 1 (snk rows) ----
  {
    const uint4* g = (const uint4*)(w1s + 16384);
    uint4* l = (uint4*)w1h;
    #pragma unroll
    for (int i = 0; i < 4; i++) l[tid + i * 512] = g[tid + i * 512];
  }
  __syncthreads();
  #pragma unroll
  for (int lk = 0; lk < 4; lk++){
    #pragma unroll
    for (int ct = 0; ct < 8; ct++){
      bf16x8 bv = *(const bf16x8*)(w1h + (((lk * 4 + quad) << 7) + ct * 16 + m) * 8);
      acc1[0][ct] = __builtin_amdgcn_mfma_f32_16x16x32_bf16(aK0[lk], bv, acc1[0][ct], 0, 0, 0);
      acc1[1][ct] = __builtin_amdgcn_mfma_f32_16x16x32_bf16(aK1[lk], bv, acc1[1][ct], 0, 0, 0);
    }
  }

  // ---- layer 2 per subtile: two 64-col phases; Yt rows wave-private ----
  #pragma unroll
  for (int s = 0; s < 2; s++){
    f32x4 acc2[4];
    #pragma unroll
    for (int ct = 0; ct < 4; ct++) acc2[ct] = z4;
    #pragma unroll
    for (int ph = 0; ph < 2; ph++){
      #pragma unroll
      for (int c = 0; c < 4; c++){
        int ct = ph * 4 + c;
        #pragma unroll
        for (int i = 0; i < 4; i++){
          float v = acc1[s][ct][i] + b1l[ct * 16 + m];
          v = v > 0.f ? v : 0.f;
          Yt[(w * 16 + quad * 4 + i) * 72 + c * 16 + m] = f2b(v);
        }
      }
      #pragma unroll
      for (int lk = 0; lk < 2; lk++){
        int ko = ph * 2 + lk;
        bf16x8 a2 = *(const bf16x8*)(Yt + (w * 16 + m) * 72 + lk * 32 + quad * 8);
        #pragma unroll
        for (int ct = 0; ct < 4; ct++){
          bf16x8 bv = *(const bf16x8*)(w2s + (((ko * 4 + quad) << 6) + ct * 16 + m) * 8);
          acc2[ct] = __builtin_amdgcn_mfma_f32_16x16x32_bf16(a2, bv, acc2[ct], 0, 0, 0);
        }
      }
    }
    // transpose C through Yt (same-wave DS ordering), store 16 SEQUENTIAL rows (2KB contiguous)
    #pragma unroll
    for (int ct = 0; ct < 4; ct++){
      #pragma unroll
      for (int i = 0; i < 4; i++){
        float v = acc2[ct][i] + b2l[ct * 16 + m];
        Yt[(w * 16 + quad * 4 + i) * 72 + ct * 16 + m] = f2b(v);
      }
    }
    int row_l = lane >> 2, seg = lane & 3;
    const uint4* tp = (const uint4*)(Yt + (w * 16 + row_l) * 72 + seg * 16);
    uint4 x0 = tp[0], x1 = tp[1];
    uint4* gp = (uint4*)(msg + (((size_t)b * Ee + ebase + s * 16 + row_l) << 6) + seg * 16);
    gp[0] = x0; gp[1] = x1;
  }
}

// ---------------- node MLP: streaming CSR gather (msg pre-sorted by sink) ----------------
__global__ __launch_bounds__(256) void node_kernel(
  float* __restrict__ sf, u16* __restrict__ sbm,
  const u16* __restrict__ msg, const int* __restrict__ rowp,
  const u16* __restrict__ w1s, const u16* __restrict__ w2s,
  const float* __restrict__ b1f, const float* __restrict__ b2f2)
{
  __shared__ __align__(16) u16 ninp[64 * 200];
  __shared__ __align__(16) u16 Yt[64 * 136];
  __shared__ float b1l[128];
  __shared__ float b2l[128];
  int b = (blockIdx.x & 7) >> 1;
  int nt = ((blockIdx.x >> 3) << 1) + (blockIdx.x & 1);
  if (nt >= 157) return;                       // uniform per block
  int n0 = nt * 64;
  int tid = threadIdx.x;
  if (tid < 128) b1l[tid] = b1f[tid];
  else b2l[tid - 128] = b2f2[tid - 128];

  {
    int nl = tid >> 2, part = tid & 3;
    int n = n0 + nl;
    float acc[16];
    #pragma unroll
    for (int i = 0; i < 16; i++) acc[i] = 0.f;
    if (n < Nn){
      int r0 = rowp[n], r1 = rowp[n + 1];
      const u16* mb = msg + (((size_t)b * Ee) << 6) + part * 16;
      for (int r = r0; r < r1; r++){
        const uint4* mp = (const uint4*)(mb + ((size_t)r << 6));
        uint4 p0 = mp[0], p1 = mp[1];
        acc2bf(acc[0], acc[1], p0.x);  acc2bf(acc[2], acc[3], p0.y);
        acc2bf(acc[4], acc[5], p0.z);  acc2bf(acc[6], acc[7], p0.w);
        acc2bf(acc[8], acc[9], p1.x);  acc2bf(acc[10], acc[11], p1.y);
        acc2bf(acc[12], acc[13], p1.z); acc2bf(acc[14], acc[15], p1.w);
      }
    }
    union { u16 h[16]; uint4 v[2]; } tb;
    #pragma unroll
    for (int i = 0; i < 16; i++) tb.h[i] = f2b(acc[i]);
    *(uint4*)(ninp + nl * 200 + part * 16) = tb.v[0];
    *(uint4*)(ninp + nl * 200 + part * 16 + 8) = tb.v[1];
    uint4* dp = (uint4*)(ninp + nl * 200 + 64 + part * 32);
    if (n < Nn){
      const uint4* sp = (const uint4*)(sbm + (((size_t)b * Nn + n) << 7) + part * 32);
      #pragma unroll
      for (int i = 0; i < 4; i++) dp[i] = sp[i];
    } else {
      uint4 zz = {0, 0, 0, 0};
      #pragma unroll
      for (int i = 0; i < 4; i++) dp[i] = zz;
    }
  }
  __syncthreads();

  int w = tid >> 6, lane = tid & 63, m = lane & 15, quad = lane >> 4;
  const f32x4 z4 = {0.f, 0.f, 0.f, 0.f};
  f32x4 acc1[8];
  #pragma unroll
  for (int ct = 0; ct < 8; ct++) acc1[ct] = z4;
  #pragma unroll 1
  for (int ks = 0; ks < 6; ks++){
    bf16x8 a = *(const bf16x8*)(ninp + (w * 16 + m) * 200 + ks * 32 + quad * 8);
    #pragma unroll
    for (int ct = 0; ct < 8; ct++){
      bf16x8 bv = *(const bf16x8*)(w1s + (((ks * 4 + quad) << 7) + ct * 16 + m) * 8);
      acc1[ct] = __builtin_amdgcn_mfma_f32_16x16x32_bf16(a, bv, acc1[ct], 0, 0, 0);
    }
  }
  #pragma unroll
  for (int ct = 0; ct < 8; ct++){
    #pragma unroll
    for (int i = 0; i < 4; i++){
      float v = acc1[ct][i] + b1l[ct * 16 + m];
      v = v > 0.f ? v : 0.f;
      Yt[(w * 16 + quad * 4 + i) * 136 + ct * 16 + m] = f2b(v);
    }
  }
  f32x4 acc2[8];
  #pragma unroll
  for (int ct = 0; ct < 8; ct++) acc2[ct] = z4;
  #pragma unroll 1
  for (int ko = 0; ko < 4; ko++){
    bf16x8 a2 = *(const bf16x8*)(Yt + (w * 16 + m) * 136 + ko * 32 + quad * 8);
    #pragma unroll
    for (int ct = 0; ct < 8; ct++){
      bf16x8 bv = *(const bf16x8*)(w2s + (((ko * 4 + quad) << 7) + ct * 16 + m) * 8);
      acc2[ct] = __builtin_amdgcn_mfma_f32_16x16x32_bf16(a2, bv, acc2[ct], 0, 0, 0);
    }
  }
  #pragma unroll
  for (int ct = 0; ct < 8; ct++){
    int u = ct * 16 + m;
    if (u < 126){
      #pragma unroll
      for (int i = 0; i < 4; i++){
        int n = n0 + w * 16 + quad * 4 + i;
        if (n < Nn){
          size_t idx = (((size_t)b * Nn + n) << 7) + 2 + u;
          float v = sf[idx] + acc2[ct][i] + b2l[u];
          sf[idx] = v;
          sbm[idx] = f2b(v);
        }
      }
    }
  }
}

// ---------------- extraction: MFMA GEMM ----------------
__global__ void swz_attn_kernel(const void* __restrict__ attn, const int* __restrict__ flag,
                                u16* __restrict__ aswz)
{
  int f = *flag;
  const long total = (long)Bx * 16 * KG * 128;
  for (long i = (long)blockIdx.x * blockDim.x + threadIdx.x; i < total; i += (long)gridDim.x * blockDim.x){
    int mj = (int)(i & 127); long r = i >> 7;
    int kg = (int)(r % KG); long r2 = r / KG;
    int qr = (int)(r2 & 15); int b = (int)(r2 >> 4);
    int mm = mj >> 3, j = mj & 7;
    int n = kg * 8 + j, q = qr * 16 + mm;
    float v = (kg < 1250) ? ldin(attn, ((long)(b * Qq + q)) * Nn + n, f) : 0.f;
    aswz[i] = f2b(v);
  }
}
__global__ void swz_s_kernel(const u16* __restrict__ sbm, u16* __restrict__ sswz)
{
  const long total = (long)Bx * KG * 128;
  for (long i = (long)blockIdx.x * blockDim.x + threadIdx.x; i < total; i += (long)gridDim.x * blockDim.x){
    int d = (int)(i & 127); long r = i >> 7;
    int kg = (int)(r % KG); int b = (int)(r / KG);
    union { u16 h[8]; uint4 v[2]; } t;
    if (kg < 1250){
      #pragma unroll
      for (int j = 0; j < 8; j++)
        t.h[j] = sbm[(((size_t)b * Nn + kg * 8 + j) << 7) + d];
    } else {
      #pragma unroll
      for (int j = 0; j < 8; j++) t.h[j] = 0;
    }
    *(uint4*)(sswz + i * 8) = t.v[0];
    *(uint4*)(sswz + i * 8 + 8) = t.v[1];
  }
}
__global__ __launch_bounds__(256) void extract2_kernel(
  const u16* __restrict__ aswz, const u16* __restrict__ sswz, float* __restrict__ part)
{
  int blk = blockIdx.x;
  int kc = blk & 15, qt = (blk >> 4) & 3, b = blk >> 6;
  int tid = threadIdx.x, w = tid >> 6, lane = tid & 63, m = lane & 15, quad = lane >> 4;
  int qr = qt * 4 + w, q0 = qr * 16;
  int kg0 = kc * 80;
  int nsteps = (kc == 15) ? 13 : 20;
  const u16* abase = aswz + ((size_t)(b * 16 + qr)) * KG * 128;
  const u16* sbase = sswz + ((size_t)b) * KG * 1024;
  f32x4 acc[8];
  const f32x4 z4 = {0.f, 0.f, 0.f, 0.f};
  #pragma unroll
  for (int ct = 0; ct < 8; ct++) acc[ct] = z4;
  #pragma unroll 1
  for (int t = 0; t < nsteps; t++){
    int kg = kg0 + t * 4 + quad;
    bf16x8 a = *(const bf16x8*)(abase + (size_t)kg * 128 + m * 8);
    #pragma unroll
    for (int ct = 0; ct < 8; ct++){
      bf16x8 bv = *(const bf16x8*)(sbase + ((size_t)kg * 128 + ct * 16 + m) * 8);
      acc[ct] = __builtin_amdgcn_mfma_f32_16x16x32_bf16(a, bv, acc[ct], 0, 0, 0);
    }
  }
  #pragma unroll
  for (int ct = 0; ct < 8; ct++){
    #pragma unroll
    for (int i = 0; i < 4; i++)
      part[(((size_t)(kc * 4 + b)) * Qq + q0 + quad * 4 + i) * 128 + ct * 16 + m] = acc[ct][i];
  }
}

// ---------------- finalize: out = [poses | sum(16 partials)] ----------------
__global__ void final_kernel(const void* __restrict__ poses, const int* __restrict__ flag,
                             const float* __restrict__ part, void* __restrict__ out)
{
  int f = *flag;
  const long total = (long)Bx * Qq * (Pp + Dd);
  for (long idx = (long)blockIdx.x * blockDim.x + threadIdx.x; idx < total; idx += (long)gridDim.x * blockDim.x){
    int j = (int)(idx % (Pp + Dd));
    long bq = idx / (Pp + Dd);
    float v;
    if (j < Pp){
      v = ldin(poses, bq * Pp + j, f);
    } else {
      int dd = j - Pp;
      int b = (int)(bq >> 8), q = (int)(bq & 255);
      v = 0.f;
      #pragma unroll
      for (int kc = 0; kc < 16; kc++)
        v += part[(((size_t)(kc * 4 + b) * Qq + q) << 7) + dd];
    }
    if (f) ((u16*)out)[idx] = f2b(v);
    else ((float*)out)[idx] = v;
  }
}

extern "C" void kernel_launch(void* const* d_in, const int* in_sizes, int n_in,
                              void* d_out, int out_size, void* d_ws, size_t ws_size,
                              hipStream_t stream)
{
  const void* in_states = d_in[0];
  const void* in_poses  = d_in[1];
  const void* in_attn   = d_in[2];
  const int*  in_src    = (const int*)d_in[3];
  const int*  in_snk    = (const int*)d_in[4];
  const void* in_w1e = d_in[5];  const void* in_b1e = d_in[6];
  const void* in_w2e = d_in[7];  const void* in_b2e = d_in[8];
  const void* in_w1n = d_in[9];  const void* in_b1n = d_in[10];
  const void* in_w2n = d_in[11]; const void* in_b2n = d_in[12];

  char* ws = (char*)d_ws;
  size_t off = 0;
  auto alloc = [&](size_t bytes){ size_t o = off; off = (off + bytes + 255) & ~(size_t)255; return o; };
  size_t o_sf   = alloc((size_t)Bx * Nn * Dd * 4);
  size_t o_sb   = alloc((size_t)Bx * Nn * Dd * 2);
  size_t o_rowp = alloc((size_t)(Nn + 1) * 4);
  size_t o_rcnt = alloc((size_t)Nn * 4);
  size_t o_psrc = alloc((size_t)Ee * 4);
  size_t o_psnk = alloc((size_t)Ee * 4);
  size_t o_w1e  = alloc(32768 * 2);
  size_t o_w2e  = alloc(8192 * 2);
  size_t o_w1n  = alloc(24576 * 2);
  size_t o_w2n  = alloc(16384 * 2);
  size_t o_b1e  = alloc(128 * 4);
  size_t o_b2e  = alloc(64 * 4);
  size_t o_b1n  = alloc(128 * 4);
  size_t o_b2n  = alloc(128 * 4);
  size_t o_flag = alloc(4);

  size_t msgPerB = (size_t)Ee * Mm * 2;            // 20.5 MB
  size_t aswzB = (size_t)Bx * 16 * KG * 128 * 2;   // 20.5 MB
  size_t sswzB = (size_t)Bx * KG * 128 * 8 * 2;    // 10.3 MB
  size_t partB = (size_t)16 * Bx * Qq * Dd * 4;    // 8.4 MB
  size_t swzTot = ((aswzB + 255) & ~(size_t)255) + ((sswzB + 255) & ~(size_t)255) + partB;
  size_t region = 4 * msgPerB;
  if (region < swzTot) region = swzTot;
  size_t o_msg = alloc(region);

  float* sf    = (float*)(ws + o_sf);
  u16*   sbm   = (u16*)(ws + o_sb);
  int*   rowp  = (int*)(ws + o_rowp);
  int*   rcnt  = (int*)(ws + o_rcnt);
  int*   psrc  = (int*)(ws + o_psrc);
  int*   psnk  = (int*)(ws + o_psnk);
  u16*   w1e_s = (u16*)(ws + o_w1e);
  u16*   w2e_s = (u16*)(ws + o_w2e);
  u16*   w1n_s = (u16*)(ws + o_w1n);
  u16*   w2n_s = (u16*)(ws + o_w2n);
  float* b1e_f = (float*)(ws + o_b1e);
  float* b2e_f = (float*)(ws + o_b2e);
  float* b1n_f = (float*)(ws + o_b1n);
  float* b2n_f = (float*)(ws + o_b2n);
  int*   flag  = (int*)(ws + o_flag);
  u16*   msg   = (u16*)(ws + o_msg);
  u16*   aswz  = (u16*)(ws + o_msg);
  u16*   sswz  = (u16*)(ws + o_msg + ((aswzB + 255) & ~(size_t)255));
  float* part  = (float*)(ws + o_msg + ((aswzB + 255) & ~(size_t)255) + ((sswzB + 255) & ~(size_t)255));

  probe_kernel<<<1, 64, 0, stream>>>(in_states, flag);
  prep_kernel<<<322, 256, 0, stream>>>(in_w1e, in_b1e, in_w2e, in_b2e,
                                       in_w1n, in_b1n, in_w2n, in_b2n, flag,
                                       w1e_s, w2e_s, w1n_s, w2n_s,
                                       b1e_f, b2e_f, b1n_f, b2n_f);
  init_states_kernel<<<1024, 256, 0, stream>>>(in_states, flag, sf, sbm);

  hipMemsetAsync(rcnt, 0, (size_t)Nn * 4, stream);
  count_kernel<<<(Ee + 255) / 256, 256, 0, stream>>>(in_snk, rcnt);
  scan_kernel<<<1, 1024, 0, stream>>>(rcnt, rowp);
  hipMemsetAsync(rcnt, 0, (size_t)Nn * 4, stream);
  fill_kernel<<<(Ee + 255) / 256, 256, 0, stream>>>(in_src, in_snk, rowp, rcnt, psrc, psnk);

  for (int step = 0; step < 3; step++){
    edge_kernel<<<2504, 512, 0, stream>>>(sbm, psrc, psnk, w1e_s, w2e_s,
                                          b1e_f, b2e_f, msg);
    node_kernel<<<632, 256, 0, stream>>>(sf, sbm, msg, rowp,
                                         w1n_s, w2n_s, b1n_f, b2n_f);
  }
  swz_attn_kernel<<<8192, 256, 0, stream>>>(in_attn, flag, aswz);
  swz_s_kernel<<<2504, 256, 0, stream>>>(sbm, sswz);
  extract2_kernel<<<256, 256, 0, stream>>>(aswz, sswz, part);
  final_kernel<<<540, 256, 0, stream>>>(in_poses, flag, part, d_out);
}